// Round 1
// baseline (2499.685 us; speedup 1.0000x reference)
//
#include <hip/hip_runtime.h>
#include <hip/hip_bf16.h>
#include <math.h>

static constexpr int NN  = 50000;   // nodes
static constexpr int NE  = 800000;  // edges
static constexpr int DIM = 128;
static constexpr int NG  = 512;     // graphs

__device__ __forceinline__ float sigm(float x) { return 1.0f / (1.0f + expf(-x)); }

// ---------------- small utility kernels ----------------
__global__ void k_zero_i(int* __restrict__ p, int n) {
    int i = blockIdx.x * blockDim.x + threadIdx.x;
    if (i < n) p[i] = 0;
}
__global__ void k_zero_f(float* __restrict__ p, int n) {
    int i = blockIdx.x * blockDim.x + threadIdx.x;
    if (i < n) p[i] = 0.0f;
}
__global__ void k_copy_i(const int* __restrict__ a, int* __restrict__ b, int n) {
    int i = blockIdx.x * blockDim.x + threadIdx.x;
    if (i < n) b[i] = a[i];
}

// gstart[g] = lower_bound(batch, g), g in [0, NG]; batch is sorted
__global__ void k_gstart(const int* __restrict__ batch, int* __restrict__ gstart, int n) {
    int g = blockIdx.x * blockDim.x + threadIdx.x;
    if (g > NG) return;
    int lo = 0, hi = n;
    while (lo < hi) { int mid = (lo + hi) >> 1; if (batch[mid] < g) lo = mid + 1; else hi = mid; }
    gstart[g] = lo;
}

__global__ void k_count(const int* __restrict__ dst, int* __restrict__ deg, int e) {
    int i = blockIdx.x * blockDim.x + threadIdx.x;
    if (i < e) atomicAdd(&deg[dst[i]], 1);
}

// single-block exclusive scan of deg[0..n) -> rowptr[0..n]
__global__ void k_scan(const int* __restrict__ deg, int* __restrict__ rowptr, int n) {
    __shared__ int s[256];
    int t = threadIdx.x;
    int chunk = (n + 255) / 256;
    int b = t * chunk; if (b > n) b = n;
    int e = b + chunk; if (e > n) e = n;
    int sum = 0;
    for (int i = b; i < e; ++i) sum += deg[i];
    s[t] = sum;
    __syncthreads();
    for (int off = 1; off < 256; off <<= 1) {
        int v = (t >= off) ? s[t - off] : 0;
        __syncthreads();
        s[t] += v;
        __syncthreads();
    }
    int base = (t > 0) ? s[t - 1] : 0;
    for (int i = b; i < e; ++i) { rowptr[i] = base; base += deg[i]; }
    if (t == 255) rowptr[n] = base;
}

__global__ void k_fill(const int* __restrict__ src, const int* __restrict__ dst,
                       int* __restrict__ cursor, int* __restrict__ csr_src, int e) {
    int i = blockIdx.x * blockDim.x + threadIdx.x;
    if (i < e) {
        int d = dst[i];
        int pos = atomicAdd(&cursor[d], 1);
        csr_src[pos] = src[i];
    }
}

// z[i] = h[i] + sum_{p} h[csr_src[p]]   (GIN aggregate incl. self)
__global__ __launch_bounds__(128) void k_aggr(const float* __restrict__ H,
                                              const int* __restrict__ rowptr,
                                              const int* __restrict__ csr,
                                              float* __restrict__ Z) {
    int i = blockIdx.x;
    int f = threadIdx.x;
    float acc = H[(size_t)i * DIM + f];
    int p0 = rowptr[i], p1 = rowptr[i + 1];
    for (int p = p0; p < p1; ++p) {
        int s = csr[p];
        acc += H[(size_t)s * DIM + f];
    }
    Z[(size_t)i * DIM + f] = acc;
}

// ---------------- GEMM helpers ----------------
// stage Wt[k][c] = Wbase[c*128 + kc + k], k in [0,32), c in [0,128); Wt stride 132
__device__ __forceinline__ void stage_wt(const float* __restrict__ Wbase, int kc,
                                         float* __restrict__ Wt, int tid) {
    #pragma unroll
    for (int idx = tid; idx < 32 * 128; idx += 256) {
        int k = idx & 31, c = idx >> 5;
        Wt[k * 132 + c] = Wbase[(size_t)c * 128 + kc + k];
    }
}

// stage 32 rows x 128 cols of A into LDS (zero-padded past n)
__device__ __forceinline__ void stage_a(const float* __restrict__ A, int rb0, int n,
                                        float* __restrict__ As, int tid) {
    #pragma unroll
    for (int idx = tid * 4; idx < 32 * 128; idx += 256 * 4) {
        int row = idx >> 7, col = idx & 127;
        float4 v = make_float4(0.f, 0.f, 0.f, 0.f);
        if (rb0 + row < n) v = *reinterpret_cast<const float4*>(A + (size_t)(rb0 + row) * 128 + col);
        *reinterpret_cast<float4*>(As + idx) = v;
    }
}

__device__ __forceinline__ void mm_chunk(const float* __restrict__ As, const float* __restrict__ Wt,
                                         int rb, int cb, int kc, float acc[4][4]) {
    #pragma unroll
    for (int k = 0; k < 32; k += 4) {
        float4 w0 = *reinterpret_cast<const float4*>(Wt + (k + 0) * 132 + cb);
        float4 w1 = *reinterpret_cast<const float4*>(Wt + (k + 1) * 132 + cb);
        float4 w2 = *reinterpret_cast<const float4*>(Wt + (k + 2) * 132 + cb);
        float4 w3 = *reinterpret_cast<const float4*>(Wt + (k + 3) * 132 + cb);
        #pragma unroll
        for (int j = 0; j < 4; ++j) {
            float4 a = *reinterpret_cast<const float4*>(As + (rb + j) * 128 + kc + k);
            acc[j][0] += a.x * w0.x + a.y * w1.x + a.z * w2.x + a.w * w3.x;
            acc[j][1] += a.x * w0.y + a.y * w1.y + a.z * w2.y + a.w * w3.y;
            acc[j][2] += a.x * w0.z + a.y * w1.z + a.z * w2.z + a.w * w3.z;
            acc[j][3] += a.x * w0.w + a.y * w1.w + a.z * w2.w + a.w * w3.w;
        }
    }
}

// C[n,128] = relu(A[n,128] @ W[128,128]^T + b)
template<bool RELU>
__global__ __launch_bounds__(256) void k_gemm128(const float* __restrict__ A,
                                                 const float* __restrict__ W,
                                                 const float* __restrict__ bias,
                                                 float* __restrict__ C, int n) {
    __shared__ float As[32 * 128];
    __shared__ float Wt[32 * 132];
    int tid = threadIdx.x;
    int rb0 = blockIdx.x * 32;
    stage_a(A, rb0, n, As, tid);
    int cb = (tid & 31) * 4;
    int rb = (tid >> 5) * 4;
    float acc[4][4];
    #pragma unroll
    for (int j = 0; j < 4; ++j)
        #pragma unroll
        for (int c = 0; c < 4; ++c) acc[j][c] = 0.f;
    for (int kc = 0; kc < 128; kc += 32) {
        __syncthreads();
        stage_wt(W, kc, Wt, tid);
        __syncthreads();
        mm_chunk(As, Wt, rb, cb, kc, acc);
    }
    float4 bv = *reinterpret_cast<const float4*>(bias + cb);
    #pragma unroll
    for (int j = 0; j < 4; ++j) {
        int row = rb0 + rb + j;
        if (row < n) {
            float4 o;
            o.x = acc[j][0] + bv.x; o.y = acc[j][1] + bv.y;
            o.z = acc[j][2] + bv.z; o.w = acc[j][3] + bv.w;
            if (RELU) {
                o.x = fmaxf(o.x, 0.f); o.y = fmaxf(o.y, 0.f);
                o.z = fmaxf(o.z, 0.f); o.w = fmaxf(o.w, 0.f);
            }
            *reinterpret_cast<float4*>(C + (size_t)row * 128 + cb) = o;
        }
    }
}

// Fused GRU step: h = GRU(m, h), PyTorch gate order r,z,n. In-place on H.
__global__ __launch_bounds__(256) void k_gru(const float* __restrict__ M,
                                             float* __restrict__ H,
                                             const float* __restrict__ Wih,
                                             const float* __restrict__ Whh,
                                             const float* __restrict__ bih,
                                             const float* __restrict__ bhh,
                                             int n) {
    __shared__ float Am[32 * 128];
    __shared__ float Ah[32 * 128];
    __shared__ float Wt[32 * 132];
    int tid = threadIdx.x;
    int rb0 = blockIdx.x * 32;
    stage_a(M, rb0, n, Am, tid);
    stage_a(H, rb0, n, Ah, tid);
    int cb = (tid & 31) * 4;
    int rb = (tid >> 5) * 4;

    float gx[3][4][4];
    #pragma unroll
    for (int g = 0; g < 3; ++g)
        #pragma unroll
        for (int j = 0; j < 4; ++j)
            #pragma unroll
            for (int c = 0; c < 4; ++c) gx[g][j][c] = 0.f;

    #pragma unroll
    for (int g = 0; g < 3; ++g) {
        for (int kc = 0; kc < 128; kc += 32) {
            __syncthreads();
            stage_wt(Wih + (size_t)g * 128 * 128, kc, Wt, tid);
            __syncthreads();
            mm_chunk(Am, Wt, rb, cb, kc, gx[g]);
        }
    }

    float rr[4][4], zz[4][4];
    #pragma unroll
    for (int g = 0; g < 3; ++g) {
        float gh[4][4];
        #pragma unroll
        for (int j = 0; j < 4; ++j)
            #pragma unroll
            for (int c = 0; c < 4; ++c) gh[j][c] = 0.f;
        for (int kc = 0; kc < 128; kc += 32) {
            __syncthreads();
            stage_wt(Whh + (size_t)g * 128 * 128, kc, Wt, tid);
            __syncthreads();
            mm_chunk(Ah, Wt, rb, cb, kc, gh);
        }
        float4 bi = *reinterpret_cast<const float4*>(bih + g * 128 + cb);
        float4 bh = *reinterpret_cast<const float4*>(bhh + g * 128 + cb);
        float biv[4] = {bi.x, bi.y, bi.z, bi.w};
        float bhv[4] = {bh.x, bh.y, bh.z, bh.w};
        if (g == 0) {
            #pragma unroll
            for (int j = 0; j < 4; ++j)
                #pragma unroll
                for (int c = 0; c < 4; ++c)
                    rr[j][c] = sigm(gx[0][j][c] + biv[c] + gh[j][c] + bhv[c]);
        } else if (g == 1) {
            #pragma unroll
            for (int j = 0; j < 4; ++j)
                #pragma unroll
                for (int c = 0; c < 4; ++c)
                    zz[j][c] = sigm(gx[1][j][c] + biv[c] + gh[j][c] + bhv[c]);
        } else {
            // n = tanh(gxn + bin + r*(ghn + bhn)); h' = (1-z)*n + z*h
            #pragma unroll
            for (int j = 0; j < 4; ++j) {
                float out[4];
                #pragma unroll
                for (int c = 0; c < 4; ++c) {
                    float nv = tanhf(gx[2][j][c] + biv[c] + rr[j][c] * (gh[j][c] + bhv[c]));
                    float hv = Ah[(rb + j) * 128 + cb + c];
                    out[c] = (1.f - zz[j][c]) * nv + zz[j][c] * hv;
                }
                int row = rb0 + rb + j;
                if (row < n) {
                    float4 o = make_float4(out[0], out[1], out[2], out[3]);
                    *reinterpret_cast<float4*>(H + (size_t)row * 128 + cb) = o;
                }
            }
        }
    }
}

// ---------------- Set2Set ----------------
// one block (128 thr) per graph: LSTM cell update
__global__ __launch_bounds__(128) void k_lstm(const float* __restrict__ qstar,
                                              const float* __restrict__ Wih,
                                              const float* __restrict__ Whh,
                                              const float* __restrict__ bih,
                                              const float* __restrict__ bhh,
                                              float* __restrict__ hl,
                                              float* __restrict__ cl) {
    int g = blockIdx.x, c = threadIdx.x;
    __shared__ float qs[2 * DIM];
    __shared__ float hs[DIM];
    qs[c] = qstar[(size_t)g * 2 * DIM + c];
    qs[DIM + c] = qstar[(size_t)g * 2 * DIM + DIM + c];
    hs[c] = hl[(size_t)g * DIM + c];
    __syncthreads();
    float gate[4];
    #pragma unroll
    for (int gg = 0; gg < 4; ++gg) {
        const float* wr = Wih + (size_t)(gg * DIM + c) * 2 * DIM;
        float acc = bih[gg * DIM + c] + bhh[gg * DIM + c];
        for (int k = 0; k < 2 * DIM; ++k) acc += wr[k] * qs[k];
        const float* wr2 = Whh + (size_t)(gg * DIM + c) * DIM;
        for (int k = 0; k < DIM; ++k) acc += wr2[k] * hs[k];
        gate[gg] = acc;
    }
    float iv = sigm(gate[0]), fv = sigm(gate[1]);
    float gv = tanhf(gate[2]), ov = sigm(gate[3]);
    float cn = fv * cl[(size_t)g * DIM + c] + iv * gv;
    cl[(size_t)g * DIM + c] = cn;
    hl[(size_t)g * DIM + c] = ov * tanhf(cn);
}

// one block (256 thr = 4 waves) per graph: attention softmax + weighted sum
__global__ __launch_bounds__(256) void k_attnpool(const float* __restrict__ H,
                                                  const float* __restrict__ hl,
                                                  const int* __restrict__ gstart,
                                                  float* __restrict__ qso) {
    int g = blockIdx.x;
    int tid = threadIdx.x, lane = tid & 63, wave = tid >> 6;
    __shared__ float q[DIM];
    __shared__ float wm[4];
    __shared__ float rv[4][DIM];
    __shared__ float sw[4];
    if (tid < DIM) q[tid] = hl[(size_t)g * DIM + tid];
    __syncthreads();
    int s = gstart[g], e = gstart[g + 1];
    float q0 = q[2 * lane], q1 = q[2 * lane + 1];
    float mx = -1e30f;
    for (int node = s + wave; node < e; node += 4) {
        float2 v = *reinterpret_cast<const float2*>(H + (size_t)node * DIM + 2 * lane);
        float p = v.x * q0 + v.y * q1;
        #pragma unroll
        for (int off = 1; off < 64; off <<= 1) p += __shfl_xor(p, off);
        mx = fmaxf(mx, p);
    }
    if (lane == 0) wm[wave] = mx;
    __syncthreads();
    mx = fmaxf(fmaxf(wm[0], wm[1]), fmaxf(wm[2], wm[3]));
    float a0 = 0.f, a1 = 0.f, sumw = 0.f;
    for (int node = s + wave; node < e; node += 4) {
        float2 v = *reinterpret_cast<const float2*>(H + (size_t)node * DIM + 2 * lane);
        float p = v.x * q0 + v.y * q1;
        #pragma unroll
        for (int off = 1; off < 64; off <<= 1) p += __shfl_xor(p, off);
        float wgt = expf(p - mx);
        sumw += wgt;
        a0 += wgt * v.x; a1 += wgt * v.y;
    }
    rv[wave][2 * lane] = a0;
    rv[wave][2 * lane + 1] = a1;
    if (lane == 0) sw[wave] = sumw;
    __syncthreads();
    if (tid < DIM) {
        float r = rv[0][tid] + rv[1][tid] + rv[2][tid] + rv[3][tid];
        float d = sw[0] + sw[1] + sw[2] + sw[3] + 1e-16f;
        qso[(size_t)g * 2 * DIM + tid] = q[tid];
        qso[(size_t)g * 2 * DIM + DIM + tid] = r / d;
    }
}

// ---------------- launch ----------------
extern "C" void kernel_launch(void* const* d_in, const int* in_sizes, int n_in,
                              void* d_out, int out_size, void* d_ws, size_t ws_size,
                              hipStream_t stream) {
    const float* x        = (const float*)d_in[0];
    const int*   ei       = (const int*)d_in[1];
    const int*   batch    = (const int*)d_in[2];
    const float* lin0_W   = (const float*)d_in[3];
    const float* lin0_b   = (const float*)d_in[4];
    const float* gin_W1   = (const float*)d_in[5];
    const float* gin_b1   = (const float*)d_in[6];
    const float* gin_W2   = (const float*)d_in[7];
    const float* gin_b2   = (const float*)d_in[8];
    const float* gru_Wih  = (const float*)d_in[9];
    const float* gru_Whh  = (const float*)d_in[10];
    const float* gru_bih  = (const float*)d_in[11];
    const float* gru_bhh  = (const float*)d_in[12];
    const float* lstm_Wih = (const float*)d_in[13];
    const float* lstm_Whh = (const float*)d_in[14];
    const float* lstm_bih = (const float*)d_in[15];
    const float* lstm_bhh = (const float*)d_in[16];

    float* qstar_out = (float*)d_out;                   // [NG, 256]
    float* h         = (float*)d_out + (size_t)NG * 2 * DIM;  // [NN, 128] == `out`

    char* w = (char*)d_ws;
    float* z    = (float*)w; w += (size_t)NN * DIM * 4;
    float* tmpb = (float*)w; w += (size_t)NN * DIM * 4;
    float* qstar= (float*)w; w += (size_t)NG * 2 * DIM * 4;
    float* hl   = (float*)w; w += (size_t)NG * DIM * 4;
    float* cl   = (float*)w; w += (size_t)NG * DIM * 4;
    int* deg    = (int*)w;   w += (size_t)(NN + 1) * 4;
    int* rowptr = (int*)w;   w += (size_t)(NN + 1) * 4;
    int* cursor = (int*)w;   w += (size_t)(NN + 1) * 4;
    int* csr_src= (int*)w;   w += (size_t)NE * 4;
    int* gstart = (int*)w;   w += (size_t)(NG + 1) * 4;

    const int* src = ei;
    const int* dst = ei + NE;

    const int nGemmBlocks = (NN + 31) / 32;

    // graph ranges + CSR build (once per call; edges are layer-invariant)
    k_gstart<<<(NG + 1 + 63) / 64, 64, 0, stream>>>(batch, gstart, NN);
    k_zero_i<<<(NN + 256) / 256, 256, 0, stream>>>(deg, NN + 1);
    k_count<<<(NE + 255) / 256, 256, 0, stream>>>(dst, deg, NE);
    k_scan<<<1, 256, 0, stream>>>(deg, rowptr, NN);
    k_copy_i<<<(NN + 255) / 256, 256, 0, stream>>>(rowptr, cursor, NN);
    k_fill<<<(NE + 255) / 256, 256, 0, stream>>>(src, dst, cursor, csr_src, NE);

    // lin0: h = relu(x @ lin0_W^T + b)
    k_gemm128<true><<<nGemmBlocks, 256, 0, stream>>>(x, lin0_W, lin0_b, h, NN);

    // 3 GC layers
    for (int t = 0; t < 3; ++t) {
        k_aggr<<<NN, 128, 0, stream>>>(h, rowptr, csr_src, z);
        k_gemm128<true><<<nGemmBlocks, 256, 0, stream>>>(z, gin_W1, gin_b1, tmpb, NN);
        k_gemm128<true><<<nGemmBlocks, 256, 0, stream>>>(tmpb, gin_W2, gin_b2, z, NN);
        k_gru<<<nGemmBlocks, 256, 0, stream>>>(z, h, gru_Wih, gru_Whh, gru_bih, gru_bhh, NN);
    }

    // Set2Set: qstar, hl, cl are contiguous in ws — zero in one shot
    k_zero_f<<<((NG * 2 * DIM + NG * DIM * 2) + 255) / 256, 256, 0, stream>>>(qstar, NG * 2 * DIM + NG * DIM * 2);
    for (int st = 0; st < 3; ++st) {
        k_lstm<<<NG, 128, 0, stream>>>(qstar, lstm_Wih, lstm_Whh, lstm_bih, lstm_bhh, hl, cl);
        k_attnpool<<<NG, 256, 0, stream>>>(h, hl, gstart, (st == 2) ? qstar_out : qstar);
    }
}

// Round 2
// 1322.825 us; speedup vs baseline: 1.8897x; 1.8897x over previous
//
#include <hip/hip_runtime.h>
#include <hip/hip_bf16.h>
#include <math.h>

static constexpr int NN  = 50000;   // nodes
static constexpr int NE  = 800000;  // edges
static constexpr int DIM = 128;
static constexpr int NG  = 512;     // graphs

typedef __attribute__((ext_vector_type(8))) short bf16x8;
typedef __attribute__((ext_vector_type(4))) float f32x4;

__device__ __forceinline__ float sigm(float x) { return 1.0f / (1.0f + expf(-x)); }
__device__ __forceinline__ float b2f(ushort u) { return __uint_as_float(((unsigned)u) << 16); }
__device__ __forceinline__ ushort f2b(float f) {
    __hip_bfloat16 h = __float2bfloat16(f);
    return *reinterpret_cast<ushort*>(&h);
}
__device__ __forceinline__ bf16x8 ldb8(const ushort* p) {
    return *reinterpret_cast<const bf16x8*>(p);
}

// ---------------- small utility kernels ----------------
__global__ void k_zero_i(int* __restrict__ p, int n) {
    int i = blockIdx.x * blockDim.x + threadIdx.x;
    if (i < n) p[i] = 0;
}
__global__ void k_zero_f(float* __restrict__ p, int n) {
    int i = blockIdx.x * blockDim.x + threadIdx.x;
    if (i < n) p[i] = 0.0f;
}
__global__ void k_copy_i(const int* __restrict__ a, int* __restrict__ b, int n) {
    int i = blockIdx.x * blockDim.x + threadIdx.x;
    if (i < n) b[i] = a[i];
}
__global__ void k_f2bv(const float* __restrict__ s, ushort* __restrict__ d, int n) {
    int i = blockIdx.x * blockDim.x + threadIdx.x;
    if (i < n) d[i] = f2b(s[i]);
}

// gstart[g] = lower_bound(batch, g), g in [0, NG]; batch is sorted
__global__ void k_gstart(const int* __restrict__ batch, int* __restrict__ gstart, int n) {
    int g = blockIdx.x * blockDim.x + threadIdx.x;
    if (g > NG) return;
    int lo = 0, hi = n;
    while (lo < hi) { int mid = (lo + hi) >> 1; if (batch[mid] < g) lo = mid + 1; else hi = mid; }
    gstart[g] = lo;
}

__global__ void k_count(const int* __restrict__ dst, int* __restrict__ deg, int e) {
    int i = blockIdx.x * blockDim.x + threadIdx.x;
    if (i < e) atomicAdd(&deg[dst[i]], 1);
}

// single-block exclusive scan of deg[0..n) -> rowptr[0..n]
__global__ void k_scan(const int* __restrict__ deg, int* __restrict__ rowptr, int n) {
    __shared__ int s[256];
    int t = threadIdx.x;
    int chunk = (n + 255) / 256;
    int b = t * chunk; if (b > n) b = n;
    int e = b + chunk; if (e > n) e = n;
    int sum = 0;
    for (int i = b; i < e; ++i) sum += deg[i];
    s[t] = sum;
    __syncthreads();
    for (int off = 1; off < 256; off <<= 1) {
        int v = (t >= off) ? s[t - off] : 0;
        __syncthreads();
        s[t] += v;
        __syncthreads();
    }
    int base = (t > 0) ? s[t - 1] : 0;
    for (int i = b; i < e; ++i) { rowptr[i] = base; base += deg[i]; }
    if (t == 255) rowptr[n] = base;
}

__global__ void k_fill(const int* __restrict__ src, const int* __restrict__ dst,
                       int* __restrict__ cursor, int* __restrict__ csr_src, int e) {
    int i = blockIdx.x * blockDim.x + threadIdx.x;
    if (i < e) {
        int d = dst[i];
        int pos = atomicAdd(&cursor[d], 1);
        csr_src[pos] = src[i];
    }
}

// z[i] = h[i] + sum_{p} h[csr_src[p]] ; bf16 in/out, fp32 accumulate.
// one wave per node, 2 bf16 (one uint) per lane.
__global__ __launch_bounds__(256) void k_aggr2(const ushort* __restrict__ Hb,
                                               const int* __restrict__ rowptr,
                                               const int* __restrict__ csr,
                                               ushort* __restrict__ Z) {
    int node = blockIdx.x * 4 + (threadIdx.x >> 6);
    if (node >= NN) return;
    int lane = threadIdx.x & 63;
    unsigned u = ((const unsigned*)(Hb + (size_t)node * DIM))[lane];
    float a0 = b2f(u & 0xffff), a1 = b2f(u >> 16);
    int p0 = rowptr[node], p1 = rowptr[node + 1];
    for (int p = p0; p < p1; ++p) {
        int s = csr[p];
        unsigned v = ((const unsigned*)(Hb + (size_t)s * DIM))[lane];
        a0 += b2f(v & 0xffff);
        a1 += b2f(v >> 16);
    }
    unsigned o = ((unsigned)f2b(a1) << 16) | (unsigned)f2b(a0);
    ((unsigned*)(Z + (size_t)node * DIM))[lane] = o;
}

// ---------------- MFMA GEMM: C[n,128] = act(A[n,128] @ W[128,128]^T + b) ----------------
// Block: 4 waves x 16 rows = 64 rows. No LDS, no barriers. W is bf16 [128][128] row-major.
// A-frag: lane l -> A[row0+(l&15)][kk*32 + (l>>4)*8 + j]  (8 contiguous k, m92/m97 layout)
// B-frag: lane l -> W[t*16+(l&15)][kk*32 + (l>>4)*8 + j]
// C/D  : lane l, reg j -> C[row0+(l>>4)*4+j][t*16+(l&15)]  (m89 layout)
template<bool AF32, bool RELU, bool WF32, bool WBF>
__global__ __launch_bounds__(256) void k_mm128(const void* __restrict__ Ap,
                                               const ushort* __restrict__ Wb,
                                               const float* __restrict__ bias,
                                               float* __restrict__ Cf,
                                               ushort* __restrict__ Cb, int n) {
    int lane = threadIdx.x & 63, wave = threadIdx.x >> 6;
    int row0 = blockIdx.x * 64 + wave * 16;
    int arow = row0 + (lane & 15);
    int ar = min(arow, n - 1);
    int kg = (lane >> 4) * 8;
    int c0 = lane & 15;
    f32x4 zero4 = {0.f, 0.f, 0.f, 0.f};
    f32x4 acc[8];
    #pragma unroll
    for (int t = 0; t < 8; ++t) acc[t] = zero4;
    #pragma unroll
    for (int kk = 0; kk < 4; ++kk) {
        bf16x8 af;
        if (AF32) {
            const float* a = (const float*)Ap + (size_t)ar * DIM + kk * 32 + kg;
            float4 x0 = *reinterpret_cast<const float4*>(a);
            float4 x1 = *reinterpret_cast<const float4*>(a + 4);
            af[0] = (short)f2b(x0.x); af[1] = (short)f2b(x0.y);
            af[2] = (short)f2b(x0.z); af[3] = (short)f2b(x0.w);
            af[4] = (short)f2b(x1.x); af[5] = (short)f2b(x1.y);
            af[6] = (short)f2b(x1.z); af[7] = (short)f2b(x1.w);
        } else {
            af = ldb8((const ushort*)Ap + (size_t)ar * DIM + kk * 32 + kg);
        }
        #pragma unroll
        for (int t = 0; t < 8; ++t) {
            bf16x8 bf = ldb8(Wb + (size_t)(t * 16 + c0) * DIM + kk * 32 + kg);
            acc[t] = __builtin_amdgcn_mfma_f32_16x16x32_bf16(af, bf, acc[t], 0, 0, 0);
        }
    }
    int rj = row0 + ((lane >> 4) << 2);
    #pragma unroll
    for (int t = 0; t < 8; ++t) {
        int col = t * 16 + c0;
        float bv = bias[col];
        #pragma unroll
        for (int j = 0; j < 4; ++j) {
            int row = rj + j;
            if (row < n) {
                float v = acc[t][j] + bv;
                if (RELU) v = fmaxf(v, 0.f);
                if (WF32) Cf[(size_t)row * DIM + col] = v;
                if (WBF)  Cb[(size_t)row * DIM + col] = f2b(v);
            }
        }
    }
}

// ---------------- fused GRU: h = GRU(m, h) ----------------
// Per gate g in {r,z,n}: gx_g = m@Wih_g^T (MFMA), gh_g = h@Whh_g^T (MFMA), then gate math.
// Never materializes gx/gh. Writes h fp32 (d_out) + bf16 copy.
__global__ __launch_bounds__(256) void k_gru2(const ushort* __restrict__ Mb,
                                              const ushort* __restrict__ Hb,
                                              const ushort* __restrict__ Wihb,
                                              const ushort* __restrict__ Whhb,
                                              const float* __restrict__ bih,
                                              const float* __restrict__ bhh,
                                              float* __restrict__ Hf,
                                              ushort* __restrict__ HbOut, int n) {
    int lane = threadIdx.x & 63, wave = threadIdx.x >> 6;
    int row0 = blockIdx.x * 64 + wave * 16;
    int arow = row0 + (lane & 15);
    int ar = min(arow, n - 1);
    int kg = (lane >> 4) * 8;
    int c0 = lane & 15;
    int rj = row0 + ((lane >> 4) << 2);
    f32x4 zero4 = {0.f, 0.f, 0.f, 0.f};
    float rg[8][4], zg[8][4];
    #pragma unroll
    for (int g = 0; g < 3; ++g) {
        f32x4 ax[8], ah[8];
        #pragma unroll
        for (int t = 0; t < 8; ++t) { ax[t] = zero4; ah[t] = zero4; }
        #pragma unroll
        for (int kk = 0; kk < 4; ++kk) {
            bf16x8 am = ldb8(Mb + (size_t)ar * DIM + kk * 32 + kg);
            bf16x8 af = ldb8(Hb + (size_t)ar * DIM + kk * 32 + kg);
            #pragma unroll
            for (int t = 0; t < 8; ++t) {
                bf16x8 bx = ldb8(Wihb + (size_t)(g * 128 + t * 16 + c0) * DIM + kk * 32 + kg);
                ax[t] = __builtin_amdgcn_mfma_f32_16x16x32_bf16(am, bx, ax[t], 0, 0, 0);
                bf16x8 bh = ldb8(Whhb + (size_t)(g * 128 + t * 16 + c0) * DIM + kk * 32 + kg);
                ah[t] = __builtin_amdgcn_mfma_f32_16x16x32_bf16(af, bh, ah[t], 0, 0, 0);
            }
        }
        #pragma unroll
        for (int t = 0; t < 8; ++t) {
            int col = t * 16 + c0;
            float bi = bih[g * 128 + col];
            float bh2 = bhh[g * 128 + col];
            #pragma unroll
            for (int j = 0; j < 4; ++j) {
                float gx = ax[t][j] + bi;
                float gh = ah[t][j] + bh2;
                if (g == 0) {
                    rg[t][j] = sigm(gx + gh);
                } else if (g == 1) {
                    zg[t][j] = sigm(gx + gh);
                } else {
                    int row = rj + j;
                    if (row < n) {
                        float nn = tanhf(gx + rg[t][j] * gh);
                        float hv = Hf[(size_t)row * DIM + col];
                        float hn = (1.f - zg[t][j]) * nn + zg[t][j] * hv;
                        Hf[(size_t)row * DIM + col] = hn;
                        HbOut[(size_t)row * DIM + col] = f2b(hn);
                    }
                }
            }
        }
    }
}

// ---------------- Set2Set ----------------
__global__ __launch_bounds__(128) void k_lstm(const float* __restrict__ qstar,
                                              const float* __restrict__ Wih,
                                              const float* __restrict__ Whh,
                                              const float* __restrict__ bih,
                                              const float* __restrict__ bhh,
                                              float* __restrict__ hl,
                                              float* __restrict__ cl) {
    int g = blockIdx.x, c = threadIdx.x;
    __shared__ float qs[2 * DIM];
    __shared__ float hs[DIM];
    qs[c] = qstar[(size_t)g * 2 * DIM + c];
    qs[DIM + c] = qstar[(size_t)g * 2 * DIM + DIM + c];
    hs[c] = hl[(size_t)g * DIM + c];
    __syncthreads();
    float gate[4];
    #pragma unroll
    for (int gg = 0; gg < 4; ++gg) {
        const float* wr = Wih + (size_t)(gg * DIM + c) * 2 * DIM;
        float acc = bih[gg * DIM + c] + bhh[gg * DIM + c];
        for (int k = 0; k < 2 * DIM; ++k) acc += wr[k] * qs[k];
        const float* wr2 = Whh + (size_t)(gg * DIM + c) * DIM;
        for (int k = 0; k < DIM; ++k) acc += wr2[k] * hs[k];
        gate[gg] = acc;
    }
    float iv = sigm(gate[0]), fv = sigm(gate[1]);
    float gv = tanhf(gate[2]), ov = sigm(gate[3]);
    float cn = fv * cl[(size_t)g * DIM + c] + iv * gv;
    cl[(size_t)g * DIM + c] = cn;
    hl[(size_t)g * DIM + c] = ov * tanhf(cn);
}

__global__ __launch_bounds__(256) void k_attnpool(const float* __restrict__ H,
                                                  const float* __restrict__ hl,
                                                  const int* __restrict__ gstart,
                                                  float* __restrict__ qso) {
    int g = blockIdx.x;
    int tid = threadIdx.x, lane = tid & 63, wave = tid >> 6;
    __shared__ float q[DIM];
    __shared__ float wm[4];
    __shared__ float rv[4][DIM];
    __shared__ float sw[4];
    if (tid < DIM) q[tid] = hl[(size_t)g * DIM + tid];
    __syncthreads();
    int s = gstart[g], e = gstart[g + 1];
    float q0 = q[2 * lane], q1 = q[2 * lane + 1];
    float mx = -1e30f;
    for (int node = s + wave; node < e; node += 4) {
        float2 v = *reinterpret_cast<const float2*>(H + (size_t)node * DIM + 2 * lane);
        float p = v.x * q0 + v.y * q1;
        #pragma unroll
        for (int off = 1; off < 64; off <<= 1) p += __shfl_xor(p, off);
        mx = fmaxf(mx, p);
    }
    if (lane == 0) wm[wave] = mx;
    __syncthreads();
    mx = fmaxf(fmaxf(wm[0], wm[1]), fmaxf(wm[2], wm[3]));
    float a0 = 0.f, a1 = 0.f, sumw = 0.f;
    for (int node = s + wave; node < e; node += 4) {
        float2 v = *reinterpret_cast<const float2*>(H + (size_t)node * DIM + 2 * lane);
        float p = v.x * q0 + v.y * q1;
        #pragma unroll
        for (int off = 1; off < 64; off <<= 1) p += __shfl_xor(p, off);
        float wgt = expf(p - mx);
        sumw += wgt;
        a0 += wgt * v.x; a1 += wgt * v.y;
    }
    rv[wave][2 * lane] = a0;
    rv[wave][2 * lane + 1] = a1;
    if (lane == 0) sw[wave] = sumw;
    __syncthreads();
    if (tid < DIM) {
        float r = rv[0][tid] + rv[1][tid] + rv[2][tid] + rv[3][tid];
        float d = sw[0] + sw[1] + sw[2] + sw[3] + 1e-16f;
        qso[(size_t)g * 2 * DIM + tid] = q[tid];
        qso[(size_t)g * 2 * DIM + DIM + tid] = r / d;
    }
}

// ---------------- launch ----------------
extern "C" void kernel_launch(void* const* d_in, const int* in_sizes, int n_in,
                              void* d_out, int out_size, void* d_ws, size_t ws_size,
                              hipStream_t stream) {
    const float* x        = (const float*)d_in[0];
    const int*   ei       = (const int*)d_in[1];
    const int*   batch    = (const int*)d_in[2];
    const float* lin0_W   = (const float*)d_in[3];
    const float* lin0_b   = (const float*)d_in[4];
    const float* gin_W1   = (const float*)d_in[5];
    const float* gin_b1   = (const float*)d_in[6];
    const float* gin_W2   = (const float*)d_in[7];
    const float* gin_b2   = (const float*)d_in[8];
    const float* gru_Wih  = (const float*)d_in[9];
    const float* gru_Whh  = (const float*)d_in[10];
    const float* gru_bih  = (const float*)d_in[11];
    const float* gru_bhh  = (const float*)d_in[12];
    const float* lstm_Wih = (const float*)d_in[13];
    const float* lstm_Whh = (const float*)d_in[14];
    const float* lstm_bih = (const float*)d_in[15];
    const float* lstm_bhh = (const float*)d_in[16];

    float* qstar_out = (float*)d_out;                         // [NG, 256]
    float* h         = (float*)d_out + (size_t)NG * 2 * DIM;  // [NN, 128] == `out`

    char* w = (char*)d_ws;
    ushort* zb    = (ushort*)w; w += (size_t)NN * DIM * 2;
    ushort* mb    = (ushort*)w; w += (size_t)NN * DIM * 2;
    ushort* hb    = (ushort*)w; w += (size_t)NN * DIM * 2;
    ushort* wlin0 = (ushort*)w; w += 16384 * 2;
    ushort* wg1   = (ushort*)w; w += 16384 * 2;
    ushort* wg2   = (ushort*)w; w += 16384 * 2;
    ushort* wih   = (ushort*)w; w += 49152 * 2;
    ushort* whh   = (ushort*)w; w += 49152 * 2;
    float* qstar  = (float*)w;  w += (size_t)NG * 2 * DIM * 4;
    float* hl     = (float*)w;  w += (size_t)NG * DIM * 4;
    float* cl     = (float*)w;  w += (size_t)NG * DIM * 4;
    int* deg      = (int*)w;    w += (size_t)(NN + 1) * 4;
    int* rowptr   = (int*)w;    w += (size_t)(NN + 1) * 4;
    int* cursor   = (int*)w;    w += (size_t)(NN + 1) * 4;
    int* csr_src  = (int*)w;    w += (size_t)NE * 4;
    int* gstart   = (int*)w;    w += (size_t)(NG + 1) * 4;

    const int* src = ei;
    const int* dst = ei + NE;

    const int nMM = (NN + 63) / 64;

    // CSR build + graph ranges (once per call)
    k_gstart<<<(NG + 1 + 63) / 64, 64, 0, stream>>>(batch, gstart, NN);
    k_zero_i<<<(NN + 256) / 256, 256, 0, stream>>>(deg, NN + 1);
    k_count<<<(NE + 255) / 256, 256, 0, stream>>>(dst, deg, NE);
    k_scan<<<1, 256, 0, stream>>>(deg, rowptr, NN);
    k_copy_i<<<(NN + 255) / 256, 256, 0, stream>>>(rowptr, cursor, NN);
    k_fill<<<(NE + 255) / 256, 256, 0, stream>>>(src, dst, cursor, csr_src, NE);

    // weights -> bf16
    k_f2bv<<<(16384 + 255) / 256, 256, 0, stream>>>(lin0_W, wlin0, 16384);
    k_f2bv<<<(16384 + 255) / 256, 256, 0, stream>>>(gin_W1, wg1, 16384);
    k_f2bv<<<(16384 + 255) / 256, 256, 0, stream>>>(gin_W2, wg2, 16384);
    k_f2bv<<<(49152 + 255) / 256, 256, 0, stream>>>(gru_Wih, wih, 49152);
    k_f2bv<<<(49152 + 255) / 256, 256, 0, stream>>>(gru_Whh, whh, 49152);

    // lin0: h = relu(x @ lin0_W^T + b)  -> fp32 h (d_out) + bf16 copy
    k_mm128<true, true, true, true><<<nMM, 256, 0, stream>>>(x, wlin0, lin0_b, h, hb, NN);

    // 3 GC layers
    for (int t = 0; t < 3; ++t) {
        k_aggr2<<<(NN + 3) / 4, 256, 0, stream>>>(hb, rowptr, csr_src, zb);
        k_mm128<false, true, false, true><<<nMM, 256, 0, stream>>>(zb, wg1, gin_b1, nullptr, mb, NN);
        k_mm128<false, true, false, true><<<nMM, 256, 0, stream>>>(mb, wg2, gin_b2, nullptr, zb, NN);
        k_gru2<<<nMM, 256, 0, stream>>>(zb, hb, wih, whh, gru_bih, gru_bhh, h, hb, NN);
    }

    // Set2Set: qstar, hl, cl contiguous -> zero in one shot
    k_zero_f<<<((NG * 2 * DIM + NG * DIM * 2) + 255) / 256, 256, 0, stream>>>(qstar, NG * 2 * DIM + NG * DIM * 2);
    for (int st = 0; st < 3; ++st) {
        k_lstm<<<NG, 128, 0, stream>>>(qstar, lstm_Wih, lstm_Whh, lstm_bih, lstm_bhh, hl, cl);
        k_attnpool<<<NG, 256, 0, stream>>>(h, hl, gstart, (st == 2) ? qstar_out : qstar);
    }
}

// Round 5
// 1151.756 us; speedup vs baseline: 2.1703x; 1.1485x over previous
//
#include <hip/hip_runtime.h>
#include <hip/hip_bf16.h>
#include <math.h>

static constexpr int NN  = 50000;   // nodes
static constexpr int NE  = 800000;  // edges
static constexpr int DIM = 128;
static constexpr int NG  = 512;     // graphs

typedef __attribute__((ext_vector_type(8))) short bf16x8;
typedef __attribute__((ext_vector_type(4))) float f32x4;

__device__ __forceinline__ float sigm(float x) { return 1.0f / (1.0f + expf(-x)); }
__device__ __forceinline__ float b2f(ushort u) { return __uint_as_float(((unsigned)u) << 16); }
__device__ __forceinline__ ushort f2b(float f) {
    __hip_bfloat16 h = __float2bfloat16(f);
    return *reinterpret_cast<ushort*>(&h);
}
__device__ __forceinline__ bf16x8 ldb8(const ushort* p) {
    return *reinterpret_cast<const bf16x8*>(p);
}

// ---------------- small utility kernels ----------------
__global__ void k_zero_i(int* __restrict__ p, int n) {
    int i = blockIdx.x * blockDim.x + threadIdx.x;
    if (i < n) p[i] = 0;
}
__global__ void k_zero_f(float* __restrict__ p, int n) {
    int i = blockIdx.x * blockDim.x + threadIdx.x;
    if (i < n) p[i] = 0.0f;
}
__global__ void k_copy_i(const int* __restrict__ a, int* __restrict__ b, int n) {
    int i = blockIdx.x * blockDim.x + threadIdx.x;
    if (i < n) b[i] = a[i];
}
__global__ void k_f2bv(const float* __restrict__ s, ushort* __restrict__ d, int n) {
    int i = blockIdx.x * blockDim.x + threadIdx.x;
    if (i < n) d[i] = f2b(s[i]);
}

// Wrz[col][k], col in [0,256): gate g=col>>7 (0=r,1=z), c=col&127.
// AB rows are [h | m]: k<128 multiplies h -> Whh; k>=128 multiplies m -> Wih.
__global__ void k_packrz(const ushort* __restrict__ wih, const ushort* __restrict__ whh,
                         ushort* __restrict__ wrz) {
    int idx = blockIdx.x * blockDim.x + threadIdx.x;
    if (idx >= 256 * 256) return;
    int col = idx >> 8, k = idx & 255;
    int g = col >> 7, c = col & 127;
    int row = g * 128 + c;
    wrz[idx] = (k < 128) ? whh[row * 128 + k] : wih[row * 128 + (k - 128)];
}
__global__ void k_biasrz(const float* __restrict__ bih, const float* __restrict__ bhh,
                         float* __restrict__ brz) {
    int col = blockIdx.x * blockDim.x + threadIdx.x;
    if (col >= 256) return;
    int g = col >> 7, c = col & 127;
    brz[col] = bih[g * 128 + c] + bhh[g * 128 + c];
}

// gstart[g] = lower_bound(batch, g)
__global__ void k_gstart(const int* __restrict__ batch, int* __restrict__ gstart, int n) {
    int g = blockIdx.x * blockDim.x + threadIdx.x;
    if (g > NG) return;
    int lo = 0, hi = n;
    while (lo < hi) { int mid = (lo + hi) >> 1; if (batch[mid] < g) lo = mid + 1; else hi = mid; }
    gstart[g] = lo;
}

__global__ void k_count(const int* __restrict__ dst, int* __restrict__ deg, int e) {
    int i = blockIdx.x * blockDim.x + threadIdx.x;
    if (i < e) atomicAdd(&deg[dst[i]], 1);
}

__global__ void k_scan(const int* __restrict__ deg, int* __restrict__ rowptr, int n) {
    __shared__ int s[256];
    int t = threadIdx.x;
    int chunk = (n + 255) / 256;
    int b = t * chunk; if (b > n) b = n;
    int e = b + chunk; if (e > n) e = n;
    int sum = 0;
    for (int i = b; i < e; ++i) sum += deg[i];
    s[t] = sum;
    __syncthreads();
    for (int off = 1; off < 256; off <<= 1) {
        int v = (t >= off) ? s[t - off] : 0;
        __syncthreads();
        s[t] += v;
        __syncthreads();
    }
    int base = (t > 0) ? s[t - 1] : 0;
    for (int i = b; i < e; ++i) { rowptr[i] = base; base += deg[i]; }
    if (t == 255) rowptr[n] = base;
}

__global__ void k_fill(const int* __restrict__ src, const int* __restrict__ dst,
                       int* __restrict__ cursor, int* __restrict__ csr_src, int e) {
    int i = blockIdx.x * blockDim.x + threadIdx.x;
    if (i < e) {
        int d = dst[i];
        int pos = atomicAdd(&cursor[d], 1);
        csr_src[pos] = src[i];
    }
}

// z[i] = h[i] + sum h[nbr]; h read from AB[:,0:128] (stride 256), z written stride 128
__global__ __launch_bounds__(256) void k_aggr3(const ushort* __restrict__ AB,
                                               const int* __restrict__ rowptr,
                                               const int* __restrict__ csr,
                                               ushort* __restrict__ Z) {
    int node = blockIdx.x * 4 + (threadIdx.x >> 6);
    if (node >= NN) return;
    int lane = threadIdx.x & 63;
    unsigned u = ((const unsigned*)(AB + (size_t)node * 256))[lane];
    float a0 = b2f(u & 0xffff), a1 = b2f(u >> 16);
    int p0 = rowptr[node], p1 = rowptr[node + 1];
    for (int p = p0; p < p1; ++p) {
        int s = csr[p];
        unsigned v = ((const unsigned*)(AB + (size_t)s * 256))[lane];
        a0 += b2f(v & 0xffff);
        a1 += b2f(v >> 16);
    }
    unsigned o = ((unsigned)f2b(a1) << 16) | (unsigned)f2b(a0);
    ((unsigned*)(Z + (size_t)node * 128))[lane] = o;
}

// ---------------- weight-stationary MFMA GEMM ----------------
// Block: 4 waves; wave w owns col-tiles {2w, 2w+1} (32 cols). grid.y selects a
// 128-col group. B-fragments live in registers; rows grid-strided.
// ACT: 0 = relu, 1 = sigmoid.
template<int KT, int MREP, int ACT>
__global__ __launch_bounds__(256) void k_wsgemm(const ushort* __restrict__ A, int AS,
                                                const ushort* __restrict__ W,
                                                const float* __restrict__ bias,
                                                ushort* __restrict__ C, int CS, int coff,
                                                int n) {
    const int K = KT * 32;
    int lane = threadIdx.x & 63, wave = threadIdx.x >> 6;
    int c0 = lane & 15, kg = (lane >> 4) * 8;
    int tb0 = wave * 32;
    const ushort* Wg = W + (size_t)blockIdx.y * 128 * K;
    const float* bg = bias + blockIdx.y * 128;
    ushort* Cg = C + coff + blockIdx.y * 128;

    bf16x8 B[2][KT];
    #pragma unroll
    for (int t = 0; t < 2; ++t)
        #pragma unroll
        for (int kk = 0; kk < KT; ++kk)
            B[t][kk] = ldb8(Wg + (size_t)(tb0 + t * 16 + c0) * K + kk * 32 + kg);

    for (int m0 = blockIdx.x * (MREP * 16); m0 < n; m0 += gridDim.x * MREP * 16) {
        f32x4 acc[MREP][2];
        #pragma unroll
        for (int m = 0; m < MREP; ++m) { acc[m][0] = {0,0,0,0}; acc[m][1] = {0,0,0,0}; }
        #pragma unroll
        for (int kk = 0; kk < KT; ++kk) {
            #pragma unroll
            for (int m = 0; m < MREP; ++m) {
                int ar = min(m0 + m * 16 + c0, n - 1);
                bf16x8 af = ldb8(A + (size_t)ar * AS + kk * 32 + kg);
                acc[m][0] = __builtin_amdgcn_mfma_f32_16x16x32_bf16(af, B[0][kk], acc[m][0], 0, 0, 0);
                acc[m][1] = __builtin_amdgcn_mfma_f32_16x16x32_bf16(af, B[1][kk], acc[m][1], 0, 0, 0);
            }
        }
        #pragma unroll
        for (int m = 0; m < MREP; ++m) {
            int rbase = m0 + m * 16 + ((lane >> 4) << 2);
            #pragma unroll
            for (int t = 0; t < 2; ++t) {
                int col = tb0 + t * 16 + c0;
                float bv = bg[col];
                #pragma unroll
                for (int j = 0; j < 4; ++j) {
                    int row = rbase + j;
                    if (row < n) {
                        float v = acc[m][t][j] + bv;
                        v = (ACT == 1) ? sigm(v) : fmaxf(v, 0.f);
                        Cg[(size_t)row * CS + col] = f2b(v);
                    }
                }
            }
        }
    }
}

// lin0: h = relu(x @ W^T + b), fp32 A; writes Hf fp32 [N,128] + AB[:,0:128] bf16
__global__ __launch_bounds__(256) void k_lin0(const float* __restrict__ X,
                                              const ushort* __restrict__ W,
                                              const float* __restrict__ bias,
                                              float* __restrict__ Hf,
                                              ushort* __restrict__ AB, int n) {
    int lane = threadIdx.x & 63, wave = threadIdx.x >> 6;
    int c0 = lane & 15, kg = (lane >> 4) * 8;
    int tb0 = wave * 32;
    bf16x8 B[2][4];
    #pragma unroll
    for (int t = 0; t < 2; ++t)
        #pragma unroll
        for (int kk = 0; kk < 4; ++kk)
            B[t][kk] = ldb8(W + (size_t)(tb0 + t * 16 + c0) * 128 + kk * 32 + kg);

    for (int m0 = blockIdx.x * 64; m0 < n; m0 += gridDim.x * 64) {
        f32x4 acc[4][2];
        #pragma unroll
        for (int m = 0; m < 4; ++m) { acc[m][0] = {0,0,0,0}; acc[m][1] = {0,0,0,0}; }
        #pragma unroll
        for (int kk = 0; kk < 4; ++kk) {
            #pragma unroll
            for (int m = 0; m < 4; ++m) {
                int ar = min(m0 + m * 16 + c0, n - 1);
                const float* a = X + (size_t)ar * 128 + kk * 32 + kg;
                float4 x0 = *reinterpret_cast<const float4*>(a);
                float4 x1 = *reinterpret_cast<const float4*>(a + 4);
                bf16x8 af;
                af[0] = (short)f2b(x0.x); af[1] = (short)f2b(x0.y);
                af[2] = (short)f2b(x0.z); af[3] = (short)f2b(x0.w);
                af[4] = (short)f2b(x1.x); af[5] = (short)f2b(x1.y);
                af[6] = (short)f2b(x1.z); af[7] = (short)f2b(x1.w);
                acc[m][0] = __builtin_amdgcn_mfma_f32_16x16x32_bf16(af, B[0][kk], acc[m][0], 0, 0, 0);
                acc[m][1] = __builtin_amdgcn_mfma_f32_16x16x32_bf16(af, B[1][kk], acc[m][1], 0, 0, 0);
            }
        }
        #pragma unroll
        for (int m = 0; m < 4; ++m) {
            int rbase = m0 + m * 16 + ((lane >> 4) << 2);
            #pragma unroll
            for (int t = 0; t < 2; ++t) {
                int col = tb0 + t * 16 + c0;
                float bv = bias[col];
                #pragma unroll
                for (int j = 0; j < 4; ++j) {
                    int row = rbase + j;
                    if (row < n) {
                        float v = fmaxf(acc[m][t][j] + bv, 0.f);
                        Hf[(size_t)row * 128 + col] = v;
                        AB[(size_t)row * 256 + col] = f2b(v);
                    }
                }
            }
        }
    }
}

// n-gate + combine: gxn = m@Wn^T, ghn = h@Un^T; h' = (1-z)*tanh(gxn+bin + r*(ghn+bhn)) + z*h.
// READS ABin (h|m), WRITES h' into ABout[:,0:128]  (disjoint buffers -> no cross-wave race).
__global__ __launch_bounds__(256) void k_ngate(const ushort* __restrict__ ABin,
                                               const ushort* __restrict__ Wn,
                                               const ushort* __restrict__ Un,
                                               const float* __restrict__ bin,
                                               const float* __restrict__ bhn,
                                               const ushort* __restrict__ rzb,
                                               float* __restrict__ Hf,
                                               ushort* __restrict__ ABout, int n) {
    int lane = threadIdx.x & 63, wave = threadIdx.x >> 6;
    int c0 = lane & 15, kg = (lane >> 4) * 8;
    int tb0 = wave * 32;
    bf16x8 Bn[2][4], Bu[2][4];
    #pragma unroll
    for (int t = 0; t < 2; ++t)
        #pragma unroll
        for (int kk = 0; kk < 4; ++kk) {
            Bn[t][kk] = ldb8(Wn + (size_t)(tb0 + t * 16 + c0) * 128 + kk * 32 + kg);
            Bu[t][kk] = ldb8(Un + (size_t)(tb0 + t * 16 + c0) * 128 + kk * 32 + kg);
        }

    for (int m0 = blockIdx.x * 32; m0 < n; m0 += gridDim.x * 32) {
        f32x4 an[2][2], au[2][2];
        #pragma unroll
        for (int m = 0; m < 2; ++m) {
            an[m][0] = {0,0,0,0}; an[m][1] = {0,0,0,0};
            au[m][0] = {0,0,0,0}; au[m][1] = {0,0,0,0};
        }
        #pragma unroll
        for (int kk = 0; kk < 4; ++kk) {
            #pragma unroll
            for (int m = 0; m < 2; ++m) {
                int ar = min(m0 + m * 16 + c0, n - 1);
                bf16x8 am = ldb8(ABin + (size_t)ar * 256 + 128 + kk * 32 + kg); // m
                bf16x8 ah = ldb8(ABin + (size_t)ar * 256 + kk * 32 + kg);       // h
                an[m][0] = __builtin_amdgcn_mfma_f32_16x16x32_bf16(am, Bn[0][kk], an[m][0], 0, 0, 0);
                an[m][1] = __builtin_amdgcn_mfma_f32_16x16x32_bf16(am, Bn[1][kk], an[m][1], 0, 0, 0);
                au[m][0] = __builtin_amdgcn_mfma_f32_16x16x32_bf16(ah, Bu[0][kk], au[m][0], 0, 0, 0);
                au[m][1] = __builtin_amdgcn_mfma_f32_16x16x32_bf16(ah, Bu[1][kk], au[m][1], 0, 0, 0);
            }
        }
        #pragma unroll
        for (int m = 0; m < 2; ++m) {
            int rbase = m0 + m * 16 + ((lane >> 4) << 2);
            #pragma unroll
            for (int t = 0; t < 2; ++t) {
                int col = tb0 + t * 16 + c0;
                float bi = bin[col], bh = bhn[col];
                #pragma unroll
                for (int j = 0; j < 4; ++j) {
                    int row = rbase + j;
                    if (row < n) {
                        float r  = b2f(rzb[(size_t)row * 256 + col]);
                        float zt = b2f(rzb[(size_t)row * 256 + 128 + col]);
                        float nn = tanhf(an[m][t][j] + bi + r * (au[m][t][j] + bh));
                        float hold = Hf[(size_t)row * 128 + col];
                        float hn = (1.f - zt) * nn + zt * hold;
                        Hf[(size_t)row * 128 + col] = hn;
                        ABout[(size_t)row * 256 + col] = f2b(hn);
                    }
                }
            }
        }
    }
}

// ---------------- Set2Set ----------------
__global__ __launch_bounds__(128) void k_lstm(const float* __restrict__ qstar,
                                              const float* __restrict__ Wih,
                                              const float* __restrict__ Whh,
                                              const float* __restrict__ bih,
                                              const float* __restrict__ bhh,
                                              float* __restrict__ hl,
                                              float* __restrict__ cl) {
    int g = blockIdx.x, c = threadIdx.x;
    __shared__ float qs[2 * DIM];
    __shared__ float hs[DIM];
    qs[c] = qstar[(size_t)g * 2 * DIM + c];
    qs[DIM + c] = qstar[(size_t)g * 2 * DIM + DIM + c];
    hs[c] = hl[(size_t)g * DIM + c];
    __syncthreads();
    float gate[4];
    #pragma unroll
    for (int gg = 0; gg < 4; ++gg) {
        const float* wr = Wih + (size_t)(gg * DIM + c) * 2 * DIM;
        float acc = bih[gg * DIM + c] + bhh[gg * DIM + c];
        for (int k = 0; k < 2 * DIM; ++k) acc += wr[k] * qs[k];
        const float* wr2 = Whh + (size_t)(gg * DIM + c) * DIM;
        for (int k = 0; k < DIM; ++k) acc += wr2[k] * hs[k];
        gate[gg] = acc;
    }
    float iv = sigm(gate[0]), fv = sigm(gate[1]);
    float gv = tanhf(gate[2]), ov = sigm(gate[3]);
    float cn = fv * cl[(size_t)g * DIM + c] + iv * gv;
    cl[(size_t)g * DIM + c] = cn;
    hl[(size_t)g * DIM + c] = ov * tanhf(cn);
}

__global__ __launch_bounds__(256) void k_attnpool(const float* __restrict__ H,
                                                  const float* __restrict__ hl,
                                                  const int* __restrict__ gstart,
                                                  float* __restrict__ qso) {
    int g = blockIdx.x;
    int tid = threadIdx.x, lane = tid & 63, wave = tid >> 6;
    __shared__ float q[DIM];
    __shared__ float wm[4];
    __shared__ float rv[4][DIM];
    __shared__ float sw[4];
    if (tid < DIM) q[tid] = hl[(size_t)g * DIM + tid];
    __syncthreads();
    int s = gstart[g], e = gstart[g + 1];
    float q0 = q[2 * lane], q1 = q[2 * lane + 1];
    float mx = -1e30f;
    for (int node = s + wave; node < e; node += 4) {
        float2 v = *reinterpret_cast<const float2*>(H + (size_t)node * DIM + 2 * lane);
        float p = v.x * q0 + v.y * q1;
        #pragma unroll
        for (int off = 1; off < 64; off <<= 1) p += __shfl_xor(p, off);
        mx = fmaxf(mx, p);
    }
    if (lane == 0) wm[wave] = mx;
    __syncthreads();
    mx = fmaxf(fmaxf(wm[0], wm[1]), fmaxf(wm[2], wm[3]));
    float a0 = 0.f, a1 = 0.f, sumw = 0.f;
    for (int node = s + wave; node < e; node += 4) {
        float2 v = *reinterpret_cast<const float2*>(H + (size_t)node * DIM + 2 * lane);
        float p = v.x * q0 + v.y * q1;
        #pragma unroll
        for (int off = 1; off < 64; off <<= 1) p += __shfl_xor(p, off);
        float wgt = expf(p - mx);
        sumw += wgt;
        a0 += wgt * v.x; a1 += wgt * v.y;
    }
    rv[wave][2 * lane] = a0;
    rv[wave][2 * lane + 1] = a1;
    if (lane == 0) sw[wave] = sumw;
    __syncthreads();
    if (tid < DIM) {
        float r = rv[0][tid] + rv[1][tid] + rv[2][tid] + rv[3][tid];
        float d = sw[0] + sw[1] + sw[2] + sw[3] + 1e-16f;
        qso[(size_t)g * 2 * DIM + tid] = q[tid];
        qso[(size_t)g * 2 * DIM + DIM + tid] = r / d;
    }
}

// ---------------- launch ----------------
extern "C" void kernel_launch(void* const* d_in, const int* in_sizes, int n_in,
                              void* d_out, int out_size, void* d_ws, size_t ws_size,
                              hipStream_t stream) {
    const float* x        = (const float*)d_in[0];
    const int*   ei       = (const int*)d_in[1];
    const int*   batch    = (const int*)d_in[2];
    const float* lin0_W   = (const float*)d_in[3];
    const float* lin0_b   = (const float*)d_in[4];
    const float* gin_W1   = (const float*)d_in[5];
    const float* gin_b1   = (const float*)d_in[6];
    const float* gin_W2   = (const float*)d_in[7];
    const float* gin_b2   = (const float*)d_in[8];
    const float* gru_Wih  = (const float*)d_in[9];
    const float* gru_Whh  = (const float*)d_in[10];
    const float* gru_bih  = (const float*)d_in[11];
    const float* gru_bhh  = (const float*)d_in[12];
    const float* lstm_Wih = (const float*)d_in[13];
    const float* lstm_Whh = (const float*)d_in[14];
    const float* lstm_bih = (const float*)d_in[15];
    const float* lstm_bhh = (const float*)d_in[16];

    float* qstar_out = (float*)d_out;                         // [NG, 256]
    float* h         = (float*)d_out + (size_t)NG * 2 * DIM;  // [NN, 128] fp32 == `out`

    char* w = (char*)d_ws;
    ushort* AB0   = (ushort*)w; w += (size_t)NN * 256 * 2;   // ping
    ushort* AB1   = (ushort*)w; w += (size_t)NN * 256 * 2;   // pong
    ushort* zt    = (ushort*)w; w += (size_t)NN * 128 * 2;   // aggr out
    ushort* t1    = (ushort*)w; w += (size_t)NN * 128 * 2;   // gin hidden
    ushort* rzb   = (ushort*)w; w += (size_t)NN * 256 * 2;   // [r | z] bf16
    ushort* wlin0 = (ushort*)w; w += 16384 * 2;
    ushort* wg1   = (ushort*)w; w += 16384 * 2;
    ushort* wg2   = (ushort*)w; w += 16384 * 2;
    ushort* wihb  = (ushort*)w; w += 49152 * 2;
    ushort* whhb  = (ushort*)w; w += 49152 * 2;
    ushort* wrz   = (ushort*)w; w += 65536 * 2;
    float* brz    = (float*)w;  w += 256 * 4;
    float* qstar  = (float*)w;  w += (size_t)NG * 2 * DIM * 4;
    float* hl     = (float*)w;  w += (size_t)NG * DIM * 4;
    float* cl     = (float*)w;  w += (size_t)NG * DIM * 4;
    int* deg      = (int*)w;    w += (size_t)(NN + 1) * 4;
    int* rowptr   = (int*)w;    w += (size_t)(NN + 1) * 4;
    int* cursor   = (int*)w;    w += (size_t)(NN + 1) * 4;
    int* csr_src  = (int*)w;    w += (size_t)NE * 4;
    int* gstart   = (int*)w;    w += (size_t)(NG + 1) * 4;

    const int* src = ei;
    const int* dst = ei + NE;

    // CSR build + graph ranges
    k_gstart<<<(NG + 1 + 63) / 64, 64, 0, stream>>>(batch, gstart, NN);
    k_zero_i<<<(NN + 256) / 256, 256, 0, stream>>>(deg, NN + 1);
    k_count<<<(NE + 255) / 256, 256, 0, stream>>>(dst, deg, NE);
    k_scan<<<1, 256, 0, stream>>>(deg, rowptr, NN);
    k_copy_i<<<(NN + 255) / 256, 256, 0, stream>>>(rowptr, cursor, NN);
    k_fill<<<(NE + 255) / 256, 256, 0, stream>>>(src, dst, cursor, csr_src, NE);

    // weights -> bf16 (+ rz pack)
    k_f2bv<<<(16384 + 255) / 256, 256, 0, stream>>>(lin0_W, wlin0, 16384);
    k_f2bv<<<(16384 + 255) / 256, 256, 0, stream>>>(gin_W1, wg1, 16384);
    k_f2bv<<<(16384 + 255) / 256, 256, 0, stream>>>(gin_W2, wg2, 16384);
    k_f2bv<<<(49152 + 255) / 256, 256, 0, stream>>>(gru_Wih, wihb, 49152);
    k_f2bv<<<(49152 + 255) / 256, 256, 0, stream>>>(gru_Whh, whhb, 49152);
    k_packrz<<<(65536 + 255) / 256, 256, 0, stream>>>(wihb, whhb, wrz);
    k_biasrz<<<1, 256, 0, stream>>>(gru_bih, gru_bhh, brz);

    // lin0 -> h (fp32) + AB0 h-columns
    k_lin0<<<391, 256, 0, stream>>>(x, wlin0, lin0_b, h, AB0, NN);

    // 3 GC layers, ping-pong AB buffers (ngate writes h' into the OTHER buffer)
    for (int t = 0; t < 3; ++t) {
        ushort* ABc = (t & 1) ? AB1 : AB0;
        ushort* ABn = (t & 1) ? AB0 : AB1;
        k_aggr3<<<(NN + 3) / 4, 256, 0, stream>>>(ABc, rowptr, csr_src, zt);
        k_wsgemm<4, 4, 0><<<dim3(391, 1), 256, 0, stream>>>(zt, 128, wg1, gin_b1, t1, 128, 0, NN);
        k_wsgemm<4, 4, 0><<<dim3(391, 1), 256, 0, stream>>>(t1, 128, wg2, gin_b2, ABc, 256, 128, NN);
        k_wsgemm<8, 4, 1><<<dim3(391, 2), 256, 0, stream>>>(ABc, 256, wrz, brz, rzb, 256, 0, NN);
        k_ngate<<<782, 256, 0, stream>>>(ABc, wihb + 256 * 128, whhb + 256 * 128,
                                         gru_bih + 256, gru_bhh + 256, rzb, h, ABn, NN);
    }

    // Set2Set
    k_zero_f<<<((NG * 2 * DIM + NG * DIM * 2) + 255) / 256, 256, 0, stream>>>(qstar, NG * 2 * DIM + NG * DIM * 2);
    for (int st = 0; st < 3; ++st) {
        k_lstm<<<NG, 128, 0, stream>>>(qstar, lstm_Wih, lstm_Whh, lstm_bih, lstm_bhh, hl, cl);
        k_attnpool<<<NG, 256, 0, stream>>>(h, hl, gstart, (st == 2) ? qstar_out : qstar);
    }
}

// Round 6
// 972.133 us; speedup vs baseline: 2.5713x; 1.1848x over previous
//
#include <hip/hip_runtime.h>
#include <hip/hip_bf16.h>
#include <math.h>

static constexpr int NN  = 50000;   // nodes
static constexpr int NE  = 800000;  // edges
static constexpr int DIM = 128;
static constexpr int NG  = 512;     // graphs

typedef __attribute__((ext_vector_type(8))) short bf16x8;
typedef __attribute__((ext_vector_type(4))) float f32x4;

__device__ __forceinline__ float sigm(float x) { return 1.0f / (1.0f + expf(-x)); }
__device__ __forceinline__ float b2f(ushort u) { return __uint_as_float(((unsigned)u) << 16); }
__device__ __forceinline__ ushort f2b(float f) {
    __hip_bfloat16 h = __float2bfloat16(f);
    return *reinterpret_cast<ushort*>(&h);
}
__device__ __forceinline__ bf16x8 ldb8(const ushort* p) {
    return *reinterpret_cast<const bf16x8*>(p);
}

// ---------------- small utility kernels ----------------
__global__ void k_zero_i(int* __restrict__ p, int n) {
    int i = blockIdx.x * blockDim.x + threadIdx.x;
    if (i < n) p[i] = 0;
}
__global__ void k_zero_f(float* __restrict__ p, int n) {
    int i = blockIdx.x * blockDim.x + threadIdx.x;
    if (i < n) p[i] = 0.0f;
}
__global__ void k_copy_i(const int* __restrict__ a, int* __restrict__ b, int n) {
    int i = blockIdx.x * blockDim.x + threadIdx.x;
    if (i < n) b[i] = a[i];
}
__global__ void k_f2bv(const float* __restrict__ s, ushort* __restrict__ d, int n) {
    int i = blockIdx.x * blockDim.x + threadIdx.x;
    if (i < n) d[i] = f2b(s[i]);
}

// Wrz[col][k], col in [0,256): gate g=col>>7 (0=r,1=z), c=col&127.
// AB rows are [h | m]: k<128 multiplies h -> Whh; k>=128 multiplies m -> Wih.
__global__ void k_packrz(const ushort* __restrict__ wih, const ushort* __restrict__ whh,
                         ushort* __restrict__ wrz) {
    int idx = blockIdx.x * blockDim.x + threadIdx.x;
    if (idx >= 256 * 256) return;
    int col = idx >> 8, k = idx & 255;
    int g = col >> 7, c = col & 127;
    int row = g * 128 + c;
    wrz[idx] = (k < 128) ? whh[row * 128 + k] : wih[row * 128 + (k - 128)];
}
__global__ void k_biasrz(const float* __restrict__ bih, const float* __restrict__ bhh,
                         float* __restrict__ brz) {
    int col = blockIdx.x * blockDim.x + threadIdx.x;
    if (col >= 256) return;
    int g = col >> 7, c = col & 127;
    brz[col] = bih[g * 128 + c] + bhh[g * 128 + c];
}

// LSTM weight transpose: Wt[k*512+col] = (k<256) ? Wih[col][k] : Whh[col][k-256]
// (gate col ordering == row ordering since col = gg*128+c)
__global__ void k_wtransL(const float* __restrict__ Wih, const float* __restrict__ Whh,
                          float* __restrict__ Wt) {
    int idx = blockIdx.x * blockDim.x + threadIdx.x;
    if (idx >= 512 * 384) return;
    int k = idx / 512, col = idx % 512;
    Wt[idx] = (k < 256) ? Wih[(size_t)col * 256 + k] : Whh[(size_t)col * 128 + (k - 256)];
}
__global__ void k_biasL(const float* __restrict__ bih, const float* __restrict__ bhh,
                        float* __restrict__ bl) {
    int col = blockIdx.x * blockDim.x + threadIdx.x;
    if (col < 512) bl[col] = bih[col] + bhh[col];
}

// gstart[g] = lower_bound(batch, g)
__global__ void k_gstart(const int* __restrict__ batch, int* __restrict__ gstart, int n) {
    int g = blockIdx.x * blockDim.x + threadIdx.x;
    if (g > NG) return;
    int lo = 0, hi = n;
    while (lo < hi) { int mid = (lo + hi) >> 1; if (batch[mid] < g) lo = mid + 1; else hi = mid; }
    gstart[g] = lo;
}

__global__ void k_count(const int* __restrict__ dst, int* __restrict__ deg, int e) {
    int i = blockIdx.x * blockDim.x + threadIdx.x;
    if (i < e) atomicAdd(&deg[dst[i]], 1);
}

__global__ void k_scan(const int* __restrict__ deg, int* __restrict__ rowptr, int n) {
    __shared__ int s[256];
    int t = threadIdx.x;
    int chunk = (n + 255) / 256;
    int b = t * chunk; if (b > n) b = n;
    int e = b + chunk; if (e > n) e = n;
    int sum = 0;
    for (int i = b; i < e; ++i) sum += deg[i];
    s[t] = sum;
    __syncthreads();
    for (int off = 1; off < 256; off <<= 1) {
        int v = (t >= off) ? s[t - off] : 0;
        __syncthreads();
        s[t] += v;
        __syncthreads();
    }
    int base = (t > 0) ? s[t - 1] : 0;
    for (int i = b; i < e; ++i) { rowptr[i] = base; base += deg[i]; }
    if (t == 255) rowptr[n] = base;
}

__global__ void k_fill(const int* __restrict__ src, const int* __restrict__ dst,
                       int* __restrict__ cursor, int* __restrict__ csr_src, int e) {
    int i = blockIdx.x * blockDim.x + threadIdx.x;
    if (i < e) {
        int d = dst[i];
        int pos = atomicAdd(&cursor[d], 1);
        csr_src[pos] = src[i];
    }
}

// z[i] = h[i] + sum h[nbr]; h read from AB[:,0:128] (stride 256), z written stride 128
__global__ __launch_bounds__(256) void k_aggr3(const ushort* __restrict__ AB,
                                               const int* __restrict__ rowptr,
                                               const int* __restrict__ csr,
                                               ushort* __restrict__ Z) {
    int node = blockIdx.x * 4 + (threadIdx.x >> 6);
    if (node >= NN) return;
    int lane = threadIdx.x & 63;
    unsigned u = ((const unsigned*)(AB + (size_t)node * 256))[lane];
    float a0 = b2f(u & 0xffff), a1 = b2f(u >> 16);
    int p0 = rowptr[node], p1 = rowptr[node + 1];
    for (int p = p0; p < p1; ++p) {
        int s = csr[p];
        unsigned v = ((const unsigned*)(AB + (size_t)s * 256))[lane];
        a0 += b2f(v & 0xffff);
        a1 += b2f(v >> 16);
    }
    unsigned o = ((unsigned)f2b(a1) << 16) | (unsigned)f2b(a0);
    ((unsigned*)(Z + (size_t)node * 128))[lane] = o;
}

// ---------------- weight-stationary MFMA GEMM ----------------
template<int KT, int MREP, int ACT>
__global__ __launch_bounds__(256) void k_wsgemm(const ushort* __restrict__ A, int AS,
                                                const ushort* __restrict__ W,
                                                const float* __restrict__ bias,
                                                ushort* __restrict__ C, int CS, int coff,
                                                int n) {
    const int K = KT * 32;
    int lane = threadIdx.x & 63, wave = threadIdx.x >> 6;
    int c0 = lane & 15, kg = (lane >> 4) * 8;
    int tb0 = wave * 32;
    const ushort* Wg = W + (size_t)blockIdx.y * 128 * K;
    const float* bg = bias + blockIdx.y * 128;
    ushort* Cg = C + coff + blockIdx.y * 128;

    bf16x8 B[2][KT];
    #pragma unroll
    for (int t = 0; t < 2; ++t)
        #pragma unroll
        for (int kk = 0; kk < KT; ++kk)
            B[t][kk] = ldb8(Wg + (size_t)(tb0 + t * 16 + c0) * K + kk * 32 + kg);

    for (int m0 = blockIdx.x * (MREP * 16); m0 < n; m0 += gridDim.x * MREP * 16) {
        f32x4 acc[MREP][2];
        #pragma unroll
        for (int m = 0; m < MREP; ++m) { acc[m][0] = {0,0,0,0}; acc[m][1] = {0,0,0,0}; }
        #pragma unroll
        for (int kk = 0; kk < KT; ++kk) {
            #pragma unroll
            for (int m = 0; m < MREP; ++m) {
                int ar = min(m0 + m * 16 + c0, n - 1);
                bf16x8 af = ldb8(A + (size_t)ar * AS + kk * 32 + kg);
                acc[m][0] = __builtin_amdgcn_mfma_f32_16x16x32_bf16(af, B[0][kk], acc[m][0], 0, 0, 0);
                acc[m][1] = __builtin_amdgcn_mfma_f32_16x16x32_bf16(af, B[1][kk], acc[m][1], 0, 0, 0);
            }
        }
        #pragma unroll
        for (int m = 0; m < MREP; ++m) {
            int rbase = m0 + m * 16 + ((lane >> 4) << 2);
            #pragma unroll
            for (int t = 0; t < 2; ++t) {
                int col = tb0 + t * 16 + c0;
                float bv = bg[col];
                #pragma unroll
                for (int j = 0; j < 4; ++j) {
                    int row = rbase + j;
                    if (row < n) {
                        float v = acc[m][t][j] + bv;
                        v = (ACT == 1) ? sigm(v) : fmaxf(v, 0.f);
                        Cg[(size_t)row * CS + col] = f2b(v);
                    }
                }
            }
        }
    }
}

// lin0: h = relu(x @ W^T + b), fp32 A; writes Hf fp32 [N,128] + AB[:,0:128] bf16
__global__ __launch_bounds__(256) void k_lin0(const float* __restrict__ X,
                                              const ushort* __restrict__ W,
                                              const float* __restrict__ bias,
                                              float* __restrict__ Hf,
                                              ushort* __restrict__ AB, int n) {
    int lane = threadIdx.x & 63, wave = threadIdx.x >> 6;
    int c0 = lane & 15, kg = (lane >> 4) * 8;
    int tb0 = wave * 32;
    bf16x8 B[2][4];
    #pragma unroll
    for (int t = 0; t < 2; ++t)
        #pragma unroll
        for (int kk = 0; kk < 4; ++kk)
            B[t][kk] = ldb8(W + (size_t)(tb0 + t * 16 + c0) * 128 + kk * 32 + kg);

    for (int m0 = blockIdx.x * 64; m0 < n; m0 += gridDim.x * 64) {
        f32x4 acc[4][2];
        #pragma unroll
        for (int m = 0; m < 4; ++m) { acc[m][0] = {0,0,0,0}; acc[m][1] = {0,0,0,0}; }
        #pragma unroll
        for (int kk = 0; kk < 4; ++kk) {
            #pragma unroll
            for (int m = 0; m < 4; ++m) {
                int ar = min(m0 + m * 16 + c0, n - 1);
                const float* a = X + (size_t)ar * 128 + kk * 32 + kg;
                float4 x0 = *reinterpret_cast<const float4*>(a);
                float4 x1 = *reinterpret_cast<const float4*>(a + 4);
                bf16x8 af;
                af[0] = (short)f2b(x0.x); af[1] = (short)f2b(x0.y);
                af[2] = (short)f2b(x0.z); af[3] = (short)f2b(x0.w);
                af[4] = (short)f2b(x1.x); af[5] = (short)f2b(x1.y);
                af[6] = (short)f2b(x1.z); af[7] = (short)f2b(x1.w);
                acc[m][0] = __builtin_amdgcn_mfma_f32_16x16x32_bf16(af, B[0][kk], acc[m][0], 0, 0, 0);
                acc[m][1] = __builtin_amdgcn_mfma_f32_16x16x32_bf16(af, B[1][kk], acc[m][1], 0, 0, 0);
            }
        }
        #pragma unroll
        for (int m = 0; m < 4; ++m) {
            int rbase = m0 + m * 16 + ((lane >> 4) << 2);
            #pragma unroll
            for (int t = 0; t < 2; ++t) {
                int col = tb0 + t * 16 + c0;
                float bv = bias[col];
                #pragma unroll
                for (int j = 0; j < 4; ++j) {
                    int row = rbase + j;
                    if (row < n) {
                        float v = fmaxf(acc[m][t][j] + bv, 0.f);
                        Hf[(size_t)row * 128 + col] = v;
                        AB[(size_t)row * 256 + col] = f2b(v);
                    }
                }
            }
        }
    }
}

// n-gate + combine (ping-pong buffers)
__global__ __launch_bounds__(256) void k_ngate(const ushort* __restrict__ ABin,
                                               const ushort* __restrict__ Wn,
                                               const ushort* __restrict__ Un,
                                               const float* __restrict__ bin,
                                               const float* __restrict__ bhn,
                                               const ushort* __restrict__ rzb,
                                               float* __restrict__ Hf,
                                               ushort* __restrict__ ABout, int n) {
    int lane = threadIdx.x & 63, wave = threadIdx.x >> 6;
    int c0 = lane & 15, kg = (lane >> 4) * 8;
    int tb0 = wave * 32;
    bf16x8 Bn[2][4], Bu[2][4];
    #pragma unroll
    for (int t = 0; t < 2; ++t)
        #pragma unroll
        for (int kk = 0; kk < 4; ++kk) {
            Bn[t][kk] = ldb8(Wn + (size_t)(tb0 + t * 16 + c0) * 128 + kk * 32 + kg);
            Bu[t][kk] = ldb8(Un + (size_t)(tb0 + t * 16 + c0) * 128 + kk * 32 + kg);
        }

    for (int m0 = blockIdx.x * 32; m0 < n; m0 += gridDim.x * 32) {
        f32x4 an[2][2], au[2][2];
        #pragma unroll
        for (int m = 0; m < 2; ++m) {
            an[m][0] = {0,0,0,0}; an[m][1] = {0,0,0,0};
            au[m][0] = {0,0,0,0}; au[m][1] = {0,0,0,0};
        }
        #pragma unroll
        for (int kk = 0; kk < 4; ++kk) {
            #pragma unroll
            for (int m = 0; m < 2; ++m) {
                int ar = min(m0 + m * 16 + c0, n - 1);
                bf16x8 am = ldb8(ABin + (size_t)ar * 256 + 128 + kk * 32 + kg); // m
                bf16x8 ah = ldb8(ABin + (size_t)ar * 256 + kk * 32 + kg);       // h
                an[m][0] = __builtin_amdgcn_mfma_f32_16x16x32_bf16(am, Bn[0][kk], an[m][0], 0, 0, 0);
                an[m][1] = __builtin_amdgcn_mfma_f32_16x16x32_bf16(am, Bn[1][kk], an[m][1], 0, 0, 0);
                au[m][0] = __builtin_amdgcn_mfma_f32_16x16x32_bf16(ah, Bu[0][kk], au[m][0], 0, 0, 0);
                au[m][1] = __builtin_amdgcn_mfma_f32_16x16x32_bf16(ah, Bu[1][kk], au[m][1], 0, 0, 0);
            }
        }
        #pragma unroll
        for (int m = 0; m < 2; ++m) {
            int rbase = m0 + m * 16 + ((lane >> 4) << 2);
            #pragma unroll
            for (int t = 0; t < 2; ++t) {
                int col = tb0 + t * 16 + c0;
                float bi = bin[col], bh = bhn[col];
                #pragma unroll
                for (int j = 0; j < 4; ++j) {
                    int row = rbase + j;
                    if (row < n) {
                        float r  = b2f(rzb[(size_t)row * 256 + col]);
                        float zt = b2f(rzb[(size_t)row * 256 + 128 + col]);
                        float nn = tanhf(an[m][t][j] + bi + r * (au[m][t][j] + bh));
                        float hold = Hf[(size_t)row * 128 + col];
                        float hn = (1.f - zt) * nn + zt * hold;
                        Hf[(size_t)row * 128 + col] = hn;
                        ABout[(size_t)row * 256 + col] = f2b(hn);
                    }
                }
            }
        }
    }
}

// ---------------- Set2Set ----------------
// LSTM cell, transposed-weight coalesced version: block per graph, 512 threads
// (one per gate column). Wt[k*512+col], k in [0,384) over [q_star | hl].
__global__ __launch_bounds__(512) void k_lstm2(const float* __restrict__ qstar,
                                               const float* __restrict__ Wt,
                                               const float* __restrict__ bl,
                                               float* __restrict__ hl,
                                               float* __restrict__ cl) {
    int g = blockIdx.x, tid = threadIdx.x;
    __shared__ float qh[384];
    __shared__ float gbuf[512];
    if (tid < 256) qh[tid] = qstar[(size_t)g * 256 + tid];
    else if (tid < 384) qh[tid] = hl[(size_t)g * 128 + (tid - 256)];
    __syncthreads();
    float acc = bl[tid];
    #pragma unroll 8
    for (int k = 0; k < 384; ++k)
        acc += Wt[(size_t)k * 512 + tid] * qh[k];
    gbuf[tid] = acc;
    __syncthreads();
    if (tid < 128) {
        float iv = sigm(gbuf[tid]);
        float fv = sigm(gbuf[128 + tid]);
        float gv = tanhf(gbuf[256 + tid]);
        float ov = sigm(gbuf[384 + tid]);
        float cn = fv * cl[(size_t)g * 128 + tid] + iv * gv;
        cl[(size_t)g * 128 + tid] = cn;
        hl[(size_t)g * 128 + tid] = ov * tanhf(cn);
    }
}

// attention softmax + weighted sum; out read as bf16 from AB h-half (stride 256)
__global__ __launch_bounds__(256) void k_attnpool(const ushort* __restrict__ AB,
                                                  const float* __restrict__ hl,
                                                  const int* __restrict__ gstart,
                                                  float* __restrict__ qso) {
    int g = blockIdx.x;
    int tid = threadIdx.x, lane = tid & 63, wave = tid >> 6;
    __shared__ float q[DIM];
    __shared__ float wm[4];
    __shared__ float rv[4][DIM];
    __shared__ float sw[4];
    if (tid < DIM) q[tid] = hl[(size_t)g * DIM + tid];
    __syncthreads();
    int s = gstart[g], e = gstart[g + 1];
    float q0 = q[2 * lane], q1 = q[2 * lane + 1];
    float mx = -1e30f;
    for (int node = s + wave; node < e; node += 4) {
        unsigned u = ((const unsigned*)(AB + (size_t)node * 256))[lane];
        float p = b2f(u & 0xffff) * q0 + b2f(u >> 16) * q1;
        #pragma unroll
        for (int off = 1; off < 64; off <<= 1) p += __shfl_xor(p, off);
        mx = fmaxf(mx, p);
    }
    if (lane == 0) wm[wave] = mx;
    __syncthreads();
    mx = fmaxf(fmaxf(wm[0], wm[1]), fmaxf(wm[2], wm[3]));
    float a0 = 0.f, a1 = 0.f, sumw = 0.f;
    for (int node = s + wave; node < e; node += 4) {
        unsigned u = ((const unsigned*)(AB + (size_t)node * 256))[lane];
        float v0 = b2f(u & 0xffff), v1 = b2f(u >> 16);
        float p = v0 * q0 + v1 * q1;
        #pragma unroll
        for (int off = 1; off < 64; off <<= 1) p += __shfl_xor(p, off);
        float wgt = expf(p - mx);
        sumw += wgt;
        a0 += wgt * v0; a1 += wgt * v1;
    }
    rv[wave][2 * lane] = a0;
    rv[wave][2 * lane + 1] = a1;
    if (lane == 0) sw[wave] = sumw;
    __syncthreads();
    if (tid < DIM) {
        float r = rv[0][tid] + rv[1][tid] + rv[2][tid] + rv[3][tid];
        float d = sw[0] + sw[1] + sw[2] + sw[3] + 1e-16f;
        qso[(size_t)g * 2 * DIM + tid] = q[tid];
        qso[(size_t)g * 2 * DIM + DIM + tid] = r / d;
    }
}

// ---------------- launch ----------------
extern "C" void kernel_launch(void* const* d_in, const int* in_sizes, int n_in,
                              void* d_out, int out_size, void* d_ws, size_t ws_size,
                              hipStream_t stream) {
    const float* x        = (const float*)d_in[0];
    const int*   ei       = (const int*)d_in[1];
    const int*   batch    = (const int*)d_in[2];
    const float* lin0_W   = (const float*)d_in[3];
    const float* lin0_b   = (const float*)d_in[4];
    const float* gin_W1   = (const float*)d_in[5];
    const float* gin_b1   = (const float*)d_in[6];
    const float* gin_W2   = (const float*)d_in[7];
    const float* gin_b2   = (const float*)d_in[8];
    const float* gru_Wih  = (const float*)d_in[9];
    const float* gru_Whh  = (const float*)d_in[10];
    const float* gru_bih  = (const float*)d_in[11];
    const float* gru_bhh  = (const float*)d_in[12];
    const float* lstm_Wih = (const float*)d_in[13];
    const float* lstm_Whh = (const float*)d_in[14];
    const float* lstm_bih = (const float*)d_in[15];
    const float* lstm_bhh = (const float*)d_in[16];

    float* qstar_out = (float*)d_out;                         // [NG, 256]
    float* h         = (float*)d_out + (size_t)NG * 2 * DIM;  // [NN, 128] fp32 == `out`

    char* w = (char*)d_ws;
    ushort* AB0   = (ushort*)w; w += (size_t)NN * 256 * 2;   // ping
    ushort* AB1   = (ushort*)w; w += (size_t)NN * 256 * 2;   // pong
    ushort* zt    = (ushort*)w; w += (size_t)NN * 128 * 2;   // aggr out
    ushort* t1    = (ushort*)w; w += (size_t)NN * 128 * 2;   // gin hidden
    ushort* rzb   = (ushort*)w; w += (size_t)NN * 256 * 2;   // [r | z] bf16
    ushort* wlin0 = (ushort*)w; w += 16384 * 2;
    ushort* wg1   = (ushort*)w; w += 16384 * 2;
    ushort* wg2   = (ushort*)w; w += 16384 * 2;
    ushort* wihb  = (ushort*)w; w += 49152 * 2;
    ushort* whhb  = (ushort*)w; w += 49152 * 2;
    ushort* wrz   = (ushort*)w; w += 65536 * 2;
    float* brz    = (float*)w;  w += 256 * 4;
    float* wltr   = (float*)w;  w += (size_t)512 * 384 * 4;  // LSTM W transposed
    float* bl     = (float*)w;  w += 512 * 4;
    float* qstar  = (float*)w;  w += (size_t)NG * 2 * DIM * 4;
    float* hl     = (float*)w;  w += (size_t)NG * DIM * 4;
    float* cl     = (float*)w;  w += (size_t)NG * DIM * 4;
    int* deg      = (int*)w;    w += (size_t)(NN + 1) * 4;
    int* rowptr   = (int*)w;    w += (size_t)(NN + 1) * 4;
    int* cursor   = (int*)w;    w += (size_t)(NN + 1) * 4;
    int* csr_src  = (int*)w;    w += (size_t)NE * 4;
    int* gstart   = (int*)w;    w += (size_t)(NG + 1) * 4;

    const int* src = ei;
    const int* dst = ei + NE;

    // CSR build + graph ranges
    k_gstart<<<(NG + 1 + 63) / 64, 64, 0, stream>>>(batch, gstart, NN);
    k_zero_i<<<(NN + 256) / 256, 256, 0, stream>>>(deg, NN + 1);
    k_count<<<(NE + 255) / 256, 256, 0, stream>>>(dst, deg, NE);
    k_scan<<<1, 256, 0, stream>>>(deg, rowptr, NN);
    k_copy_i<<<(NN + 255) / 256, 256, 0, stream>>>(rowptr, cursor, NN);
    k_fill<<<(NE + 255) / 256, 256, 0, stream>>>(src, dst, cursor, csr_src, NE);

    // weights -> bf16 (+ rz pack, LSTM transpose)
    k_f2bv<<<(16384 + 255) / 256, 256, 0, stream>>>(lin0_W, wlin0, 16384);
    k_f2bv<<<(16384 + 255) / 256, 256, 0, stream>>>(gin_W1, wg1, 16384);
    k_f2bv<<<(16384 + 255) / 256, 256, 0, stream>>>(gin_W2, wg2, 16384);
    k_f2bv<<<(49152 + 255) / 256, 256, 0, stream>>>(gru_Wih, wihb, 49152);
    k_f2bv<<<(49152 + 255) / 256, 256, 0, stream>>>(gru_Whh, whhb, 49152);
    k_packrz<<<(65536 + 255) / 256, 256, 0, stream>>>(wihb, whhb, wrz);
    k_biasrz<<<1, 256, 0, stream>>>(gru_bih, gru_bhh, brz);
    k_wtransL<<<(512 * 384 + 255) / 256, 256, 0, stream>>>(lstm_Wih, lstm_Whh, wltr);
    k_biasL<<<2, 256, 0, stream>>>(lstm_bih, lstm_bhh, bl);

    // lin0 -> h (fp32) + AB0 h-columns
    k_lin0<<<391, 256, 0, stream>>>(x, wlin0, lin0_b, h, AB0, NN);

    // 3 GC layers, ping-pong AB buffers (ngate writes h' into the OTHER buffer)
    for (int t = 0; t < 3; ++t) {
        ushort* ABc = (t & 1) ? AB1 : AB0;
        ushort* ABn = (t & 1) ? AB0 : AB1;
        k_aggr3<<<(NN + 3) / 4, 256, 0, stream>>>(ABc, rowptr, csr_src, zt);
        k_wsgemm<4, 4, 0><<<dim3(391, 1), 256, 0, stream>>>(zt, 128, wg1, gin_b1, t1, 128, 0, NN);
        k_wsgemm<4, 4, 0><<<dim3(391, 1), 256, 0, stream>>>(t1, 128, wg2, gin_b2, ABc, 256, 128, NN);
        k_wsgemm<8, 4, 1><<<dim3(391, 2), 256, 0, stream>>>(ABc, 256, wrz, brz, rzb, 256, 0, NN);
        k_ngate<<<782, 256, 0, stream>>>(ABc, wihb + 256 * 128, whhb + 256 * 128,
                                         gru_bih + 256, gru_bhh + 256, rzb, h, ABn, NN);
    }
    // final bf16 h lives in AB1 (t=2 wrote ABn=AB1)
    const ushort* ABfin = AB1;

    // Set2Set
    k_zero_f<<<((NG * 2 * DIM + NG * DIM * 2) + 255) / 256, 256, 0, stream>>>(qstar, NG * 2 * DIM + NG * DIM * 2);
    for (int st = 0; st < 3; ++st) {
        k_lstm2<<<NG, 512, 0, stream>>>(qstar, wltr, bl, hl, cl);
        k_attnpool<<<NG, 256, 0, stream>>>(ABfin, hl, gstart, (st == 2) ? qstar_out : qstar);
    }
}

// Round 7
// 893.375 us; speedup vs baseline: 2.7980x; 1.0882x over previous
//
#include <hip/hip_runtime.h>
#include <hip/hip_bf16.h>
#include <math.h>

static constexpr int NN  = 50000;   // nodes
static constexpr int NE  = 800000;  // edges
static constexpr int DIM = 128;
static constexpr int NG  = 512;     // graphs
static constexpr int NBLK = (NN + 255) / 256;  // 196 scan blocks

typedef __attribute__((ext_vector_type(8))) short bf16x8;
typedef __attribute__((ext_vector_type(4))) float f32x4;

__device__ __forceinline__ float sigm(float x) { return 1.0f / (1.0f + expf(-x)); }
__device__ __forceinline__ float b2f(ushort u) { return __uint_as_float(((unsigned)u) << 16); }
__device__ __forceinline__ ushort f2b(float f) {
    __hip_bfloat16 h = __float2bfloat16(f);
    return *reinterpret_cast<ushort*>(&h);
}
__device__ __forceinline__ bf16x8 ldb8(const ushort* p) {
    return *reinterpret_cast<const bf16x8*>(p);
}

// ---------------- small utility kernels ----------------
__global__ void k_zero_i(int* __restrict__ p, int n) {
    int i = blockIdx.x * blockDim.x + threadIdx.x;
    if (i < n) p[i] = 0;
}
__global__ void k_zero_f(float* __restrict__ p, int n) {
    int i = blockIdx.x * blockDim.x + threadIdx.x;
    if (i < n) p[i] = 0.0f;
}
__global__ void k_f2bv(const float* __restrict__ s, ushort* __restrict__ d, int n) {
    int i = blockIdx.x * blockDim.x + threadIdx.x;
    if (i < n) d[i] = f2b(s[i]);
}

// Wrz[col][k], col in [0,256): gate g=col>>7 (0=r,1=z), c=col&127.
// AB rows are [h | m]: k<128 multiplies h -> Whh; k>=128 multiplies m -> Wih.
__global__ void k_packrz(const ushort* __restrict__ wih, const ushort* __restrict__ whh,
                         ushort* __restrict__ wrz) {
    int idx = blockIdx.x * blockDim.x + threadIdx.x;
    if (idx >= 256 * 256) return;
    int col = idx >> 8, k = idx & 255;
    int g = col >> 7, c = col & 127;
    int row = g * 128 + c;
    wrz[idx] = (k < 128) ? whh[row * 128 + k] : wih[row * 128 + (k - 128)];
}
__global__ void k_biasrz(const float* __restrict__ bih, const float* __restrict__ bhh,
                         float* __restrict__ brz) {
    int col = blockIdx.x * blockDim.x + threadIdx.x;
    if (col >= 256) return;
    int g = col >> 7, c = col & 127;
    brz[col] = bih[g * 128 + c] + bhh[g * 128 + c];
}

// LSTM weight transpose: Wt[k*512+col] = (k<256) ? Wih[col][k] : Whh[col][k-256]
__global__ void k_wtransL(const float* __restrict__ Wih, const float* __restrict__ Whh,
                          float* __restrict__ Wt) {
    int idx = blockIdx.x * blockDim.x + threadIdx.x;
    if (idx >= 512 * 384) return;
    int k = idx / 512, col = idx % 512;
    Wt[idx] = (k < 256) ? Wih[(size_t)col * 256 + k] : Whh[(size_t)col * 128 + (k - 256)];
}
__global__ void k_biasL(const float* __restrict__ bih, const float* __restrict__ bhh,
                        float* __restrict__ bl) {
    int col = blockIdx.x * blockDim.x + threadIdx.x;
    if (col < 512) bl[col] = bih[col] + bhh[col];
}

// gstart[g] = lower_bound(batch, g)
__global__ void k_gstart(const int* __restrict__ batch, int* __restrict__ gstart, int n) {
    int g = blockIdx.x * blockDim.x + threadIdx.x;
    if (g > NG) return;
    int lo = 0, hi = n;
    while (lo < hi) { int mid = (lo + hi) >> 1; if (batch[mid] < g) lo = mid + 1; else hi = mid; }
    gstart[g] = lo;
}

__global__ void k_count(const int* __restrict__ dst, int* __restrict__ deg, int e) {
    int i = blockIdx.x * blockDim.x + threadIdx.x;
    if (i < e) atomicAdd(&deg[dst[i]], 1);
}

// ---------------- parallel 3-phase exclusive scan of deg -> rowptr/cursor ----------------
// Phase A: per-block exclusive scan (partial) + block totals
__global__ __launch_bounds__(256) void k_scan_blk(const int* __restrict__ deg,
                                                  int* __restrict__ part,
                                                  int* __restrict__ blksum) {
    __shared__ int s[256];
    int b = blockIdx.x, t = threadIdx.x;
    int i = b * 256 + t;
    int v = (i < NN) ? deg[i] : 0;
    s[t] = v;
    __syncthreads();
    #pragma unroll
    for (int off = 1; off < 256; off <<= 1) {
        int x = (t >= off) ? s[t - off] : 0;
        __syncthreads();
        s[t] += x;
        __syncthreads();
    }
    if (i < NN) part[i] = s[t] - v;           // exclusive within block
    if (t == 255) blksum[b] = s[255];
}
// Phase B: single small block scans the 196 block sums -> exclusive offsets + total
__global__ __launch_bounds__(256) void k_scan_top(const int* __restrict__ blksum,
                                                  int* __restrict__ blkoff) {
    __shared__ int s[256];
    int t = threadIdx.x;
    int v = (t < NBLK) ? blksum[t] : 0;
    s[t] = v;
    __syncthreads();
    #pragma unroll
    for (int off = 1; off < 256; off <<= 1) {
        int x = (t >= off) ? s[t - off] : 0;
        __syncthreads();
        s[t] += x;
        __syncthreads();
    }
    if (t < NBLK) blkoff[t] = s[t] - v;
    if (t == NBLK - 1) blkoff[NBLK] = s[t];   // grand total
}
// Phase C: add offsets, write rowptr AND cursor (fuses the old copy kernel)
__global__ __launch_bounds__(256) void k_scan_add(const int* __restrict__ part,
                                                  const int* __restrict__ blkoff,
                                                  int* __restrict__ rowptr,
                                                  int* __restrict__ cursor) {
    int b = blockIdx.x, t = threadIdx.x;
    int i = b * 256 + t;
    if (i < NN) {
        int r = part[i] + blkoff[b];
        rowptr[i] = r;
        cursor[i] = r;
    }
    if (b == 0 && t == 0) rowptr[NN] = blkoff[NBLK];
}

__global__ void k_fill(const int* __restrict__ src, const int* __restrict__ dst,
                       int* __restrict__ cursor, int* __restrict__ csr_src, int e) {
    int i = blockIdx.x * blockDim.x + threadIdx.x;
    if (i < e) {
        int d = dst[i];
        int pos = atomicAdd(&cursor[d], 1);
        csr_src[pos] = src[i];
    }
}

// z[i] = h[i] + sum h[nbr]; h read from AB[:,0:128] (stride 256), z written stride 128
__global__ __launch_bounds__(256) void k_aggr3(const ushort* __restrict__ AB,
                                               const int* __restrict__ rowptr,
                                               const int* __restrict__ csr,
                                               ushort* __restrict__ Z) {
    int node = blockIdx.x * 4 + (threadIdx.x >> 6);
    if (node >= NN) return;
    int lane = threadIdx.x & 63;
    unsigned u = ((const unsigned*)(AB + (size_t)node * 256))[lane];
    float a0 = b2f(u & 0xffff), a1 = b2f(u >> 16);
    int p0 = rowptr[node], p1 = rowptr[node + 1];
    for (int p = p0; p < p1; ++p) {
        int s = csr[p];
        unsigned v = ((const unsigned*)(AB + (size_t)s * 256))[lane];
        a0 += b2f(v & 0xffff);
        a1 += b2f(v >> 16);
    }
    unsigned o = ((unsigned)f2b(a1) << 16) | (unsigned)f2b(a0);
    ((unsigned*)(Z + (size_t)node * 128))[lane] = o;
}

// ---------------- weight-stationary MFMA GEMM ----------------
template<int KT, int MREP, int ACT>
__global__ __launch_bounds__(256) void k_wsgemm(const ushort* __restrict__ A, int AS,
                                                const ushort* __restrict__ W,
                                                const float* __restrict__ bias,
                                                ushort* __restrict__ C, int CS, int coff,
                                                int n) {
    const int K = KT * 32;
    int lane = threadIdx.x & 63, wave = threadIdx.x >> 6;
    int c0 = lane & 15, kg = (lane >> 4) * 8;
    int tb0 = wave * 32;
    const ushort* Wg = W + (size_t)blockIdx.y * 128 * K;
    const float* bg = bias + blockIdx.y * 128;
    ushort* Cg = C + coff + blockIdx.y * 128;

    bf16x8 B[2][KT];
    #pragma unroll
    for (int t = 0; t < 2; ++t)
        #pragma unroll
        for (int kk = 0; kk < KT; ++kk)
            B[t][kk] = ldb8(Wg + (size_t)(tb0 + t * 16 + c0) * K + kk * 32 + kg);

    for (int m0 = blockIdx.x * (MREP * 16); m0 < n; m0 += gridDim.x * MREP * 16) {
        f32x4 acc[MREP][2];
        #pragma unroll
        for (int m = 0; m < MREP; ++m) { acc[m][0] = {0,0,0,0}; acc[m][1] = {0,0,0,0}; }
        #pragma unroll
        for (int kk = 0; kk < KT; ++kk) {
            #pragma unroll
            for (int m = 0; m < MREP; ++m) {
                int ar = min(m0 + m * 16 + c0, n - 1);
                bf16x8 af = ldb8(A + (size_t)ar * AS + kk * 32 + kg);
                acc[m][0] = __builtin_amdgcn_mfma_f32_16x16x32_bf16(af, B[0][kk], acc[m][0], 0, 0, 0);
                acc[m][1] = __builtin_amdgcn_mfma_f32_16x16x32_bf16(af, B[1][kk], acc[m][1], 0, 0, 0);
            }
        }
        #pragma unroll
        for (int m = 0; m < MREP; ++m) {
            int rbase = m0 + m * 16 + ((lane >> 4) << 2);
            #pragma unroll
            for (int t = 0; t < 2; ++t) {
                int col = tb0 + t * 16 + c0;
                float bv = bg[col];
                #pragma unroll
                for (int j = 0; j < 4; ++j) {
                    int row = rbase + j;
                    if (row < n) {
                        float v = acc[m][t][j] + bv;
                        v = (ACT == 1) ? sigm(v) : fmaxf(v, 0.f);
                        Cg[(size_t)row * CS + col] = f2b(v);
                    }
                }
            }
        }
    }
}

// lin0: h = relu(x @ W^T + b), fp32 A; writes Hf fp32 [N,128] + AB[:,0:128] bf16
__global__ __launch_bounds__(256) void k_lin0(const float* __restrict__ X,
                                              const ushort* __restrict__ W,
                                              const float* __restrict__ bias,
                                              float* __restrict__ Hf,
                                              ushort* __restrict__ AB, int n) {
    int lane = threadIdx.x & 63, wave = threadIdx.x >> 6;
    int c0 = lane & 15, kg = (lane >> 4) * 8;
    int tb0 = wave * 32;
    bf16x8 B[2][4];
    #pragma unroll
    for (int t = 0; t < 2; ++t)
        #pragma unroll
        for (int kk = 0; kk < 4; ++kk)
            B[t][kk] = ldb8(W + (size_t)(tb0 + t * 16 + c0) * 128 + kk * 32 + kg);

    for (int m0 = blockIdx.x * 64; m0 < n; m0 += gridDim.x * 64) {
        f32x4 acc[4][2];
        #pragma unroll
        for (int m = 0; m < 4; ++m) { acc[m][0] = {0,0,0,0}; acc[m][1] = {0,0,0,0}; }
        #pragma unroll
        for (int kk = 0; kk < 4; ++kk) {
            #pragma unroll
            for (int m = 0; m < 4; ++m) {
                int ar = min(m0 + m * 16 + c0, n - 1);
                const float* a = X + (size_t)ar * 128 + kk * 32 + kg;
                float4 x0 = *reinterpret_cast<const float4*>(a);
                float4 x1 = *reinterpret_cast<const float4*>(a + 4);
                bf16x8 af;
                af[0] = (short)f2b(x0.x); af[1] = (short)f2b(x0.y);
                af[2] = (short)f2b(x0.z); af[3] = (short)f2b(x0.w);
                af[4] = (short)f2b(x1.x); af[5] = (short)f2b(x1.y);
                af[6] = (short)f2b(x1.z); af[7] = (short)f2b(x1.w);
                acc[m][0] = __builtin_amdgcn_mfma_f32_16x16x32_bf16(af, B[0][kk], acc[m][0], 0, 0, 0);
                acc[m][1] = __builtin_amdgcn_mfma_f32_16x16x32_bf16(af, B[1][kk], acc[m][1], 0, 0, 0);
            }
        }
        #pragma unroll
        for (int m = 0; m < 4; ++m) {
            int rbase = m0 + m * 16 + ((lane >> 4) << 2);
            #pragma unroll
            for (int t = 0; t < 2; ++t) {
                int col = tb0 + t * 16 + c0;
                float bv = bias[col];
                #pragma unroll
                for (int j = 0; j < 4; ++j) {
                    int row = rbase + j;
                    if (row < n) {
                        float v = fmaxf(acc[m][t][j] + bv, 0.f);
                        Hf[(size_t)row * 128 + col] = v;
                        AB[(size_t)row * 256 + col] = f2b(v);
                    }
                }
            }
        }
    }
}

// n-gate + combine (ping-pong buffers)
__global__ __launch_bounds__(256) void k_ngate(const ushort* __restrict__ ABin,
                                               const ushort* __restrict__ Wn,
                                               const ushort* __restrict__ Un,
                                               const float* __restrict__ bin,
                                               const float* __restrict__ bhn,
                                               const ushort* __restrict__ rzb,
                                               float* __restrict__ Hf,
                                               ushort* __restrict__ ABout, int n) {
    int lane = threadIdx.x & 63, wave = threadIdx.x >> 6;
    int c0 = lane & 15, kg = (lane >> 4) * 8;
    int tb0 = wave * 32;
    bf16x8 Bn[2][4], Bu[2][4];
    #pragma unroll
    for (int t = 0; t < 2; ++t)
        #pragma unroll
        for (int kk = 0; kk < 4; ++kk) {
            Bn[t][kk] = ldb8(Wn + (size_t)(tb0 + t * 16 + c0) * 128 + kk * 32 + kg);
            Bu[t][kk] = ldb8(Un + (size_t)(tb0 + t * 16 + c0) * 128 + kk * 32 + kg);
        }

    for (int m0 = blockIdx.x * 32; m0 < n; m0 += gridDim.x * 32) {
        f32x4 an[2][2], au[2][2];
        #pragma unroll
        for (int m = 0; m < 2; ++m) {
            an[m][0] = {0,0,0,0}; an[m][1] = {0,0,0,0};
            au[m][0] = {0,0,0,0}; au[m][1] = {0,0,0,0};
        }
        #pragma unroll
        for (int kk = 0; kk < 4; ++kk) {
            #pragma unroll
            for (int m = 0; m < 2; ++m) {
                int ar = min(m0 + m * 16 + c0, n - 1);
                bf16x8 am = ldb8(ABin + (size_t)ar * 256 + 128 + kk * 32 + kg); // m
                bf16x8 ah = ldb8(ABin + (size_t)ar * 256 + kk * 32 + kg);       // h
                an[m][0] = __builtin_amdgcn_mfma_f32_16x16x32_bf16(am, Bn[0][kk], an[m][0], 0, 0, 0);
                an[m][1] = __builtin_amdgcn_mfma_f32_16x16x32_bf16(am, Bn[1][kk], an[m][1], 0, 0, 0);
                au[m][0] = __builtin_amdgcn_mfma_f32_16x16x32_bf16(ah, Bu[0][kk], au[m][0], 0, 0, 0);
                au[m][1] = __builtin_amdgcn_mfma_f32_16x16x32_bf16(ah, Bu[1][kk], au[m][1], 0, 0, 0);
            }
        }
        #pragma unroll
        for (int m = 0; m < 2; ++m) {
            int rbase = m0 + m * 16 + ((lane >> 4) << 2);
            #pragma unroll
            for (int t = 0; t < 2; ++t) {
                int col = tb0 + t * 16 + c0;
                float bi = bin[col], bh = bhn[col];
                #pragma unroll
                for (int j = 0; j < 4; ++j) {
                    int row = rbase + j;
                    if (row < n) {
                        float r  = b2f(rzb[(size_t)row * 256 + col]);
                        float zt = b2f(rzb[(size_t)row * 256 + 128 + col]);
                        float nn = tanhf(an[m][t][j] + bi + r * (au[m][t][j] + bh));
                        float hold = Hf[(size_t)row * 128 + col];
                        float hn = (1.f - zt) * nn + zt * hold;
                        Hf[(size_t)row * 128 + col] = hn;
                        ABout[(size_t)row * 256 + col] = f2b(hn);
                    }
                }
            }
        }
    }
}

// ---------------- Set2Set ----------------
__global__ __launch_bounds__(512) void k_lstm2(const float* __restrict__ qstar,
                                               const float* __restrict__ Wt,
                                               const float* __restrict__ bl,
                                               float* __restrict__ hl,
                                               float* __restrict__ cl) {
    int g = blockIdx.x, tid = threadIdx.x;
    __shared__ float qh[384];
    __shared__ float gbuf[512];
    if (tid < 256) qh[tid] = qstar[(size_t)g * 256 + tid];
    else if (tid < 384) qh[tid] = hl[(size_t)g * 128 + (tid - 256)];
    __syncthreads();
    float acc = bl[tid];
    #pragma unroll 8
    for (int k = 0; k < 384; ++k)
        acc += Wt[(size_t)k * 512 + tid] * qh[k];
    gbuf[tid] = acc;
    __syncthreads();
    if (tid < 128) {
        float iv = sigm(gbuf[tid]);
        float fv = sigm(gbuf[128 + tid]);
        float gv = tanhf(gbuf[256 + tid]);
        float ov = sigm(gbuf[384 + tid]);
        float cn = fv * cl[(size_t)g * 128 + tid] + iv * gv;
        cl[(size_t)g * 128 + tid] = cn;
        hl[(size_t)g * 128 + tid] = ov * tanhf(cn);
    }
}

// attention softmax + weighted sum; out read as bf16 from AB h-half (stride 256)
__global__ __launch_bounds__(256) void k_attnpool(const ushort* __restrict__ AB,
                                                  const float* __restrict__ hl,
                                                  const int* __restrict__ gstart,
                                                  float* __restrict__ qso) {
    int g = blockIdx.x;
    int tid = threadIdx.x, lane = tid & 63, wave = tid >> 6;
    __shared__ float q[DIM];
    __shared__ float wm[4];
    __shared__ float rv[4][DIM];
    __shared__ float sw[4];
    if (tid < DIM) q[tid] = hl[(size_t)g * DIM + tid];
    __syncthreads();
    int s = gstart[g], e = gstart[g + 1];
    float q0 = q[2 * lane], q1 = q[2 * lane + 1];
    float mx = -1e30f;
    for (int node = s + wave; node < e; node += 4) {
        unsigned u = ((const unsigned*)(AB + (size_t)node * 256))[lane];
        float p = b2f(u & 0xffff) * q0 + b2f(u >> 16) * q1;
        #pragma unroll
        for (int off = 1; off < 64; off <<= 1) p += __shfl_xor(p, off);
        mx = fmaxf(mx, p);
    }
    if (lane == 0) wm[wave] = mx;
    __syncthreads();
    mx = fmaxf(fmaxf(wm[0], wm[1]), fmaxf(wm[2], wm[3]));
    float a0 = 0.f, a1 = 0.f, sumw = 0.f;
    for (int node = s + wave; node < e; node += 4) {
        unsigned u = ((const unsigned*)(AB + (size_t)node * 256))[lane];
        float v0 = b2f(u & 0xffff), v1 = b2f(u >> 16);
        float p = v0 * q0 + v1 * q1;
        #pragma unroll
        for (int off = 1; off < 64; off <<= 1) p += __shfl_xor(p, off);
        float wgt = expf(p - mx);
        sumw += wgt;
        a0 += wgt * v0; a1 += wgt * v1;
    }
    rv[wave][2 * lane] = a0;
    rv[wave][2 * lane + 1] = a1;
    if (lane == 0) sw[wave] = sumw;
    __syncthreads();
    if (tid < DIM) {
        float r = rv[0][tid] + rv[1][tid] + rv[2][tid] + rv[3][tid];
        float d = sw[0] + sw[1] + sw[2] + sw[3] + 1e-16f;
        qso[(size_t)g * 2 * DIM + tid] = q[tid];
        qso[(size_t)g * 2 * DIM + DIM + tid] = r / d;
    }
}

// ---------------- launch ----------------
extern "C" void kernel_launch(void* const* d_in, const int* in_sizes, int n_in,
                              void* d_out, int out_size, void* d_ws, size_t ws_size,
                              hipStream_t stream) {
    const float* x        = (const float*)d_in[0];
    const int*   ei       = (const int*)d_in[1];
    const int*   batch    = (const int*)d_in[2];
    const float* lin0_W   = (const float*)d_in[3];
    const float* lin0_b   = (const float*)d_in[4];
    const float* gin_W1   = (const float*)d_in[5];
    const float* gin_b1   = (const float*)d_in[6];
    const float* gin_W2   = (const float*)d_in[7];
    const float* gin_b2   = (const float*)d_in[8];
    const float* gru_Wih  = (const float*)d_in[9];
    const float* gru_Whh  = (const float*)d_in[10];
    const float* gru_bih  = (const float*)d_in[11];
    const float* gru_bhh  = (const float*)d_in[12];
    const float* lstm_Wih = (const float*)d_in[13];
    const float* lstm_Whh = (const float*)d_in[14];
    const float* lstm_bih = (const float*)d_in[15];
    const float* lstm_bhh = (const float*)d_in[16];

    float* qstar_out = (float*)d_out;                         // [NG, 256]
    float* h         = (float*)d_out + (size_t)NG * 2 * DIM;  // [NN, 128] fp32 == `out`

    char* w = (char*)d_ws;
    ushort* AB0   = (ushort*)w; w += (size_t)NN * 256 * 2;   // ping
    ushort* AB1   = (ushort*)w; w += (size_t)NN * 256 * 2;   // pong
    ushort* zt    = (ushort*)w; w += (size_t)NN * 128 * 2;   // aggr out
    ushort* t1    = (ushort*)w; w += (size_t)NN * 128 * 2;   // gin hidden
    ushort* rzb   = (ushort*)w; w += (size_t)NN * 256 * 2;   // [r | z] bf16
    ushort* wlin0 = (ushort*)w; w += 16384 * 2;
    ushort* wg1   = (ushort*)w; w += 16384 * 2;
    ushort* wg2   = (ushort*)w; w += 16384 * 2;
    ushort* wihb  = (ushort*)w; w += 49152 * 2;
    ushort* whhb  = (ushort*)w; w += 49152 * 2;
    ushort* wrz   = (ushort*)w; w += 65536 * 2;
    float* brz    = (float*)w;  w += 256 * 4;
    float* wltr   = (float*)w;  w += (size_t)512 * 384 * 4;  // LSTM W transposed
    float* bl     = (float*)w;  w += 512 * 4;
    float* qstar  = (float*)w;  w += (size_t)NG * 2 * DIM * 4;
    float* hl     = (float*)w;  w += (size_t)NG * DIM * 4;
    float* cl     = (float*)w;  w += (size_t)NG * DIM * 4;
    int* deg      = (int*)w;    w += (size_t)(NN + 1) * 4;
    int* rowptr   = (int*)w;    w += (size_t)(NN + 1) * 4;
    int* cursor   = (int*)w;    w += (size_t)(NN + 1) * 4;
    int* csr_src  = (int*)w;    w += (size_t)NE * 4;
    int* gstart   = (int*)w;    w += (size_t)(NG + 1) * 4;
    int* part     = (int*)w;    w += (size_t)NN * 4;
    int* blksum   = (int*)w;    w += (size_t)(NBLK + 1) * 4;
    int* blkoff   = (int*)w;    w += (size_t)(NBLK + 1) * 4;

    const int* src = ei;
    const int* dst = ei + NE;

    // CSR build + graph ranges (parallel scan)
    k_gstart<<<(NG + 1 + 63) / 64, 64, 0, stream>>>(batch, gstart, NN);
    k_zero_i<<<(NN + 256) / 256, 256, 0, stream>>>(deg, NN + 1);
    k_count<<<(NE + 255) / 256, 256, 0, stream>>>(dst, deg, NE);
    k_scan_blk<<<NBLK, 256, 0, stream>>>(deg, part, blksum);
    k_scan_top<<<1, 256, 0, stream>>>(blksum, blkoff);
    k_scan_add<<<NBLK, 256, 0, stream>>>(part, blkoff, rowptr, cursor);
    k_fill<<<(NE + 255) / 256, 256, 0, stream>>>(src, dst, cursor, csr_src, NE);

    // weights -> bf16 (+ rz pack, LSTM transpose)
    k_f2bv<<<(16384 + 255) / 256, 256, 0, stream>>>(lin0_W, wlin0, 16384);
    k_f2bv<<<(16384 + 255) / 256, 256, 0, stream>>>(gin_W1, wg1, 16384);
    k_f2bv<<<(16384 + 255) / 256, 256, 0, stream>>>(gin_W2, wg2, 16384);
    k_f2bv<<<(49152 + 255) / 256, 256, 0, stream>>>(gru_Wih, wihb, 49152);
    k_f2bv<<<(49152 + 255) / 256, 256, 0, stream>>>(gru_Whh, whhb, 49152);
    k_packrz<<<(65536 + 255) / 256, 256, 0, stream>>>(wihb, whhb, wrz);
    k_biasrz<<<1, 256, 0, stream>>>(gru_bih, gru_bhh, brz);
    k_wtransL<<<(512 * 384 + 255) / 256, 256, 0, stream>>>(lstm_Wih, lstm_Whh, wltr);
    k_biasL<<<2, 256, 0, stream>>>(lstm_bih, lstm_bhh, bl);

    // lin0 -> h (fp32) + AB0 h-columns
    k_lin0<<<391, 256, 0, stream>>>(x, wlin0, lin0_b, h, AB0, NN);

    // 3 GC layers, ping-pong AB buffers (ngate writes h' into the OTHER buffer)
    for (int t = 0; t < 3; ++t) {
        ushort* ABc = (t & 1) ? AB1 : AB0;
        ushort* ABn = (t & 1) ? AB0 : AB1;
        k_aggr3<<<(NN + 3) / 4, 256, 0, stream>>>(ABc, rowptr, csr_src, zt);
        k_wsgemm<4, 4, 0><<<dim3(391, 1), 256, 0, stream>>>(zt, 128, wg1, gin_b1, t1, 128, 0, NN);
        k_wsgemm<4, 4, 0><<<dim3(391, 1), 256, 0, stream>>>(t1, 128, wg2, gin_b2, ABc, 256, 128, NN);
        k_wsgemm<8, 4, 1><<<dim3(391, 2), 256, 0, stream>>>(ABc, 256, wrz, brz, rzb, 256, 0, NN);
        k_ngate<<<782, 256, 0, stream>>>(ABc, wihb + 256 * 128, whhb + 256 * 128,
                                         gru_bih + 256, gru_bhh + 256, rzb, h, ABn, NN);
    }
    // final bf16 h lives in AB1 (t=2 wrote ABn=AB1)
    const ushort* ABfin = AB1;

    // Set2Set
    k_zero_f<<<((NG * 2 * DIM + NG * DIM * 2) + 255) / 256, 256, 0, stream>>>(qstar, NG * 2 * DIM + NG * DIM * 2);
    for (int st = 0; st < 3; ++st) {
        k_lstm2<<<NG, 512, 0, stream>>>(qstar, wltr, bl, hl, cl);
        k_attnpool<<<NG, 256, 0, stream>>>(ABfin, hl, gstart, (st == 2) ? qstar_out : qstar);
    }
}

// Round 8
// 758.144 us; speedup vs baseline: 3.2971x; 1.1784x over previous
//
#include <hip/hip_runtime.h>
#include <hip/hip_bf16.h>
#include <math.h>

static constexpr int NN  = 50000;   // nodes
static constexpr int NE  = 800000;  // edges
static constexpr int DIM = 128;
static constexpr int NG  = 512;     // graphs
static constexpr int NBLK = (NN + 255) / 256;  // 196 scan blocks

typedef __attribute__((ext_vector_type(8))) short bf16x8;
typedef __attribute__((ext_vector_type(4))) float f32x4;

__device__ __forceinline__ float sigm(float x) { return 1.0f / (1.0f + expf(-x)); }
__device__ __forceinline__ float b2f(ushort u) { return __uint_as_float(((unsigned)u) << 16); }
__device__ __forceinline__ ushort f2b(float f) {
    __hip_bfloat16 h = __float2bfloat16(f);
    return *reinterpret_cast<ushort*>(&h);
}
__device__ __forceinline__ bf16x8 ldb8(const ushort* p) {
    return *reinterpret_cast<const bf16x8*>(p);
}

// ---------------- small utility kernels ----------------
__global__ void k_zero_i(int* __restrict__ p, int n) {
    int i = blockIdx.x * blockDim.x + threadIdx.x;
    if (i < n) p[i] = 0;
}
__global__ void k_zero_f(float* __restrict__ p, int n) {
    int i = blockIdx.x * blockDim.x + threadIdx.x;
    if (i < n) p[i] = 0.0f;
}
__global__ void k_f2bv(const float* __restrict__ s, ushort* __restrict__ d, int n) {
    int i = blockIdx.x * blockDim.x + threadIdx.x;
    if (i < n) d[i] = f2b(s[i]);
}

// Wrz[col][k], col in [0,256): gate g=col>>7 (0=r,1=z), c=col&127.
// AB rows are [h | m]: k<128 multiplies h -> Whh; k>=128 multiplies m -> Wih.
__global__ void k_packrz(const ushort* __restrict__ wih, const ushort* __restrict__ whh,
                         ushort* __restrict__ wrz) {
    int idx = blockIdx.x * blockDim.x + threadIdx.x;
    if (idx >= 256 * 256) return;
    int col = idx >> 8, k = idx & 255;
    int g = col >> 7, c = col & 127;
    int row = g * 128 + c;
    wrz[idx] = (k < 128) ? whh[row * 128 + k] : wih[row * 128 + (k - 128)];
}
__global__ void k_biasrz(const float* __restrict__ bih, const float* __restrict__ bhh,
                         float* __restrict__ brz) {
    int col = blockIdx.x * blockDim.x + threadIdx.x;
    if (col >= 256) return;
    int g = col >> 7, c = col & 127;
    brz[col] = bih[g * 128 + c] + bhh[g * 128 + c];
}

// LSTM weight transpose: Wt[k*512+col] = (k<256) ? Wih[col][k] : Whh[col][k-256]
__global__ void k_wtransL(const float* __restrict__ Wih, const float* __restrict__ Whh,
                          float* __restrict__ Wt) {
    int idx = blockIdx.x * blockDim.x + threadIdx.x;
    if (idx >= 512 * 384) return;
    int k = idx / 512, col = idx % 512;
    Wt[idx] = (k < 256) ? Wih[(size_t)col * 256 + k] : Whh[(size_t)col * 128 + (k - 256)];
}
__global__ void k_biasL(const float* __restrict__ bih, const float* __restrict__ bhh,
                        float* __restrict__ bl) {
    int col = blockIdx.x * blockDim.x + threadIdx.x;
    if (col < 512) bl[col] = bih[col] + bhh[col];
}

// gstart[g] = lower_bound(batch, g)
__global__ void k_gstart(const int* __restrict__ batch, int* __restrict__ gstart, int n) {
    int g = blockIdx.x * blockDim.x + threadIdx.x;
    if (g > NG) return;
    int lo = 0, hi = n;
    while (lo < hi) { int mid = (lo + hi) >> 1; if (batch[mid] < g) lo = mid + 1; else hi = mid; }
    gstart[g] = lo;
}

__global__ void k_count(const int* __restrict__ dst, int* __restrict__ deg, int e) {
    int i = blockIdx.x * blockDim.x + threadIdx.x;
    if (i < e) atomicAdd(&deg[dst[i]], 1);
}

// ---------------- parallel 3-phase exclusive scan of deg -> rowptr/cursor ----------------
__global__ __launch_bounds__(256) void k_scan_blk(const int* __restrict__ deg,
                                                  int* __restrict__ part,
                                                  int* __restrict__ blksum) {
    __shared__ int s[256];
    int b = blockIdx.x, t = threadIdx.x;
    int i = b * 256 + t;
    int v = (i < NN) ? deg[i] : 0;
    s[t] = v;
    __syncthreads();
    #pragma unroll
    for (int off = 1; off < 256; off <<= 1) {
        int x = (t >= off) ? s[t - off] : 0;
        __syncthreads();
        s[t] += x;
        __syncthreads();
    }
    if (i < NN) part[i] = s[t] - v;
    if (t == 255) blksum[b] = s[255];
}
__global__ __launch_bounds__(256) void k_scan_top(const int* __restrict__ blksum,
                                                  int* __restrict__ blkoff) {
    __shared__ int s[256];
    int t = threadIdx.x;
    int v = (t < NBLK) ? blksum[t] : 0;
    s[t] = v;
    __syncthreads();
    #pragma unroll
    for (int off = 1; off < 256; off <<= 1) {
        int x = (t >= off) ? s[t - off] : 0;
        __syncthreads();
        s[t] += x;
        __syncthreads();
    }
    if (t < NBLK) blkoff[t] = s[t] - v;
    if (t == NBLK - 1) blkoff[NBLK] = s[t];
}
__global__ __launch_bounds__(256) void k_scan_add(const int* __restrict__ part,
                                                  const int* __restrict__ blkoff,
                                                  int* __restrict__ rowptr,
                                                  int* __restrict__ cursor) {
    int b = blockIdx.x, t = threadIdx.x;
    int i = b * 256 + t;
    if (i < NN) {
        int r = part[i] + blkoff[b];
        rowptr[i] = r;
        cursor[i] = r;
    }
    if (b == 0 && t == 0) rowptr[NN] = blkoff[NBLK];
}

__global__ void k_fill(const int* __restrict__ src, const int* __restrict__ dst,
                       int* __restrict__ cursor, int* __restrict__ csr_src, int e) {
    int i = blockIdx.x * blockDim.x + threadIdx.x;
    if (i < e) {
        int d = dst[i];
        int pos = atomicAdd(&cursor[d], 1);
        csr_src[pos] = src[i];
    }
}

// z[i] = h[i] + sum h[nbr]; unroll-by-4 gather with independent acc chains (4x MLP)
__global__ __launch_bounds__(256) void k_aggr4(const ushort* __restrict__ AB,
                                               const int* __restrict__ rowptr,
                                               const int* __restrict__ csr,
                                               ushort* __restrict__ Z) {
    int node = blockIdx.x * 4 + (threadIdx.x >> 6);
    if (node >= NN) return;
    int lane = threadIdx.x & 63;
    const unsigned* base = (const unsigned*)AB;
    unsigned u = base[(size_t)node * 128 + lane];
    float a0 = b2f(u & 0xffff), a1 = b2f(u >> 16);
    float b0 = 0.f, b1 = 0.f, c0 = 0.f, c1 = 0.f, d0 = 0.f, d1 = 0.f;
    int p = rowptr[node], p1 = rowptr[node + 1];
    for (; p + 4 <= p1; p += 4) {
        int s0 = csr[p], s1 = csr[p + 1], s2 = csr[p + 2], s3 = csr[p + 3];
        unsigned v0 = base[(size_t)s0 * 128 + lane];
        unsigned v1 = base[(size_t)s1 * 128 + lane];
        unsigned v2 = base[(size_t)s2 * 128 + lane];
        unsigned v3 = base[(size_t)s3 * 128 + lane];
        a0 += b2f(v0 & 0xffff); a1 += b2f(v0 >> 16);
        b0 += b2f(v1 & 0xffff); b1 += b2f(v1 >> 16);
        c0 += b2f(v2 & 0xffff); c1 += b2f(v2 >> 16);
        d0 += b2f(v3 & 0xffff); d1 += b2f(v3 >> 16);
    }
    for (; p < p1; ++p) {
        int s = csr[p];
        unsigned v = base[(size_t)s * 128 + lane];
        a0 += b2f(v & 0xffff); a1 += b2f(v >> 16);
    }
    a0 += b0 + c0 + d0;
    a1 += b1 + c1 + d1;
    unsigned o = ((unsigned)f2b(a1) << 16) | (unsigned)f2b(a0);
    ((unsigned*)(Z + (size_t)node * 128))[lane] = o;
}

// ---------------- weight-stationary MFMA GEMM ----------------
template<int KT, int MREP, int ACT>
__global__ __launch_bounds__(256) void k_wsgemm(const ushort* __restrict__ A, int AS,
                                                const ushort* __restrict__ W,
                                                const float* __restrict__ bias,
                                                ushort* __restrict__ C, int CS, int coff,
                                                int n) {
    const int K = KT * 32;
    int lane = threadIdx.x & 63, wave = threadIdx.x >> 6;
    int c0 = lane & 15, kg = (lane >> 4) * 8;
    int tb0 = wave * 32;
    const ushort* Wg = W + (size_t)blockIdx.y * 128 * K;
    const float* bg = bias + blockIdx.y * 128;
    ushort* Cg = C + coff + blockIdx.y * 128;

    bf16x8 B[2][KT];
    #pragma unroll
    for (int t = 0; t < 2; ++t)
        #pragma unroll
        for (int kk = 0; kk < KT; ++kk)
            B[t][kk] = ldb8(Wg + (size_t)(tb0 + t * 16 + c0) * K + kk * 32 + kg);

    for (int m0 = blockIdx.x * (MREP * 16); m0 < n; m0 += gridDim.x * MREP * 16) {
        f32x4 acc[MREP][2];
        #pragma unroll
        for (int m = 0; m < MREP; ++m) { acc[m][0] = {0,0,0,0}; acc[m][1] = {0,0,0,0}; }
        #pragma unroll
        for (int kk = 0; kk < KT; ++kk) {
            #pragma unroll
            for (int m = 0; m < MREP; ++m) {
                int ar = min(m0 + m * 16 + c0, n - 1);
                bf16x8 af = ldb8(A + (size_t)ar * AS + kk * 32 + kg);
                acc[m][0] = __builtin_amdgcn_mfma_f32_16x16x32_bf16(af, B[0][kk], acc[m][0], 0, 0, 0);
                acc[m][1] = __builtin_amdgcn_mfma_f32_16x16x32_bf16(af, B[1][kk], acc[m][1], 0, 0, 0);
            }
        }
        #pragma unroll
        for (int m = 0; m < MREP; ++m) {
            int rbase = m0 + m * 16 + ((lane >> 4) << 2);
            #pragma unroll
            for (int t = 0; t < 2; ++t) {
                int col = tb0 + t * 16 + c0;
                float bv = bg[col];
                #pragma unroll
                for (int j = 0; j < 4; ++j) {
                    int row = rbase + j;
                    if (row < n) {
                        float v = acc[m][t][j] + bv;
                        v = (ACT == 1) ? sigm(v) : fmaxf(v, 0.f);
                        Cg[(size_t)row * CS + col] = f2b(v);
                    }
                }
            }
        }
    }
}

// lin0: h = relu(x @ W^T + b), fp32 A; writes AB[:,0:128] bf16 only
__global__ __launch_bounds__(256) void k_lin0(const float* __restrict__ X,
                                              const ushort* __restrict__ W,
                                              const float* __restrict__ bias,
                                              ushort* __restrict__ AB, int n) {
    int lane = threadIdx.x & 63, wave = threadIdx.x >> 6;
    int c0 = lane & 15, kg = (lane >> 4) * 8;
    int tb0 = wave * 32;
    bf16x8 B[2][4];
    #pragma unroll
    for (int t = 0; t < 2; ++t)
        #pragma unroll
        for (int kk = 0; kk < 4; ++kk)
            B[t][kk] = ldb8(W + (size_t)(tb0 + t * 16 + c0) * 128 + kk * 32 + kg);

    for (int m0 = blockIdx.x * 64; m0 < n; m0 += gridDim.x * 64) {
        f32x4 acc[4][2];
        #pragma unroll
        for (int m = 0; m < 4; ++m) { acc[m][0] = {0,0,0,0}; acc[m][1] = {0,0,0,0}; }
        #pragma unroll
        for (int kk = 0; kk < 4; ++kk) {
            #pragma unroll
            for (int m = 0; m < 4; ++m) {
                int ar = min(m0 + m * 16 + c0, n - 1);
                const float* a = X + (size_t)ar * 128 + kk * 32 + kg;
                float4 x0 = *reinterpret_cast<const float4*>(a);
                float4 x1 = *reinterpret_cast<const float4*>(a + 4);
                bf16x8 af;
                af[0] = (short)f2b(x0.x); af[1] = (short)f2b(x0.y);
                af[2] = (short)f2b(x0.z); af[3] = (short)f2b(x0.w);
                af[4] = (short)f2b(x1.x); af[5] = (short)f2b(x1.y);
                af[6] = (short)f2b(x1.z); af[7] = (short)f2b(x1.w);
                acc[m][0] = __builtin_amdgcn_mfma_f32_16x16x32_bf16(af, B[0][kk], acc[m][0], 0, 0, 0);
                acc[m][1] = __builtin_amdgcn_mfma_f32_16x16x32_bf16(af, B[1][kk], acc[m][1], 0, 0, 0);
            }
        }
        #pragma unroll
        for (int m = 0; m < 4; ++m) {
            int rbase = m0 + m * 16 + ((lane >> 4) << 2);
            #pragma unroll
            for (int t = 0; t < 2; ++t) {
                int col = tb0 + t * 16 + c0;
                float bv = bias[col];
                #pragma unroll
                for (int j = 0; j < 4; ++j) {
                    int row = rbase + j;
                    if (row < n) {
                        float v = fmaxf(acc[m][t][j] + bv, 0.f);
                        AB[(size_t)row * 256 + col] = f2b(v);
                    }
                }
            }
        }
    }
}

// n-gate + combine. h_old read as bf16 from ABin; Hf written only when WRITEH (last layer).
template<bool WRITEH>
__global__ __launch_bounds__(256) void k_ngate(const ushort* __restrict__ ABin,
                                               const ushort* __restrict__ Wn,
                                               const ushort* __restrict__ Un,
                                               const float* __restrict__ bin,
                                               const float* __restrict__ bhn,
                                               const ushort* __restrict__ rzb,
                                               float* __restrict__ Hf,
                                               ushort* __restrict__ ABout, int n) {
    int lane = threadIdx.x & 63, wave = threadIdx.x >> 6;
    int c0 = lane & 15, kg = (lane >> 4) * 8;
    int tb0 = wave * 32;
    bf16x8 Bn[2][4], Bu[2][4];
    #pragma unroll
    for (int t = 0; t < 2; ++t)
        #pragma unroll
        for (int kk = 0; kk < 4; ++kk) {
            Bn[t][kk] = ldb8(Wn + (size_t)(tb0 + t * 16 + c0) * 128 + kk * 32 + kg);
            Bu[t][kk] = ldb8(Un + (size_t)(tb0 + t * 16 + c0) * 128 + kk * 32 + kg);
        }

    for (int m0 = blockIdx.x * 32; m0 < n; m0 += gridDim.x * 32) {
        f32x4 an[2][2], au[2][2];
        #pragma unroll
        for (int m = 0; m < 2; ++m) {
            an[m][0] = {0,0,0,0}; an[m][1] = {0,0,0,0};
            au[m][0] = {0,0,0,0}; au[m][1] = {0,0,0,0};
        }
        #pragma unroll
        for (int kk = 0; kk < 4; ++kk) {
            #pragma unroll
            for (int m = 0; m < 2; ++m) {
                int ar = min(m0 + m * 16 + c0, n - 1);
                bf16x8 am = ldb8(ABin + (size_t)ar * 256 + 128 + kk * 32 + kg); // m
                bf16x8 ah = ldb8(ABin + (size_t)ar * 256 + kk * 32 + kg);       // h
                an[m][0] = __builtin_amdgcn_mfma_f32_16x16x32_bf16(am, Bn[0][kk], an[m][0], 0, 0, 0);
                an[m][1] = __builtin_amdgcn_mfma_f32_16x16x32_bf16(am, Bn[1][kk], an[m][1], 0, 0, 0);
                au[m][0] = __builtin_amdgcn_mfma_f32_16x16x32_bf16(ah, Bu[0][kk], au[m][0], 0, 0, 0);
                au[m][1] = __builtin_amdgcn_mfma_f32_16x16x32_bf16(ah, Bu[1][kk], au[m][1], 0, 0, 0);
            }
        }
        #pragma unroll
        for (int m = 0; m < 2; ++m) {
            int rbase = m0 + m * 16 + ((lane >> 4) << 2);
            #pragma unroll
            for (int t = 0; t < 2; ++t) {
                int col = tb0 + t * 16 + c0;
                float bi = bin[col], bh = bhn[col];
                #pragma unroll
                for (int j = 0; j < 4; ++j) {
                    int row = rbase + j;
                    if (row < n) {
                        float r  = b2f(rzb[(size_t)row * 256 + col]);
                        float zt = b2f(rzb[(size_t)row * 256 + 128 + col]);
                        float nn = tanhf(an[m][t][j] + bi + r * (au[m][t][j] + bh));
                        float hold = b2f(ABin[(size_t)row * 256 + col]);
                        float hn = (1.f - zt) * nn + zt * hold;
                        if (WRITEH) Hf[(size_t)row * 128 + col] = hn;
                        ABout[(size_t)row * 256 + col] = f2b(hn);
                    }
                }
            }
        }
    }
}

// ---------------- Set2Set ----------------
__global__ __launch_bounds__(512) void k_lstm2(const float* __restrict__ qstar,
                                               const float* __restrict__ Wt,
                                               const float* __restrict__ bl,
                                               float* __restrict__ hl,
                                               float* __restrict__ cl) {
    int g = blockIdx.x, tid = threadIdx.x;
    __shared__ float qh[384];
    __shared__ float gbuf[512];
    if (tid < 256) qh[tid] = qstar[(size_t)g * 256 + tid];
    else if (tid < 384) qh[tid] = hl[(size_t)g * 128 + (tid - 256)];
    __syncthreads();
    float acc = bl[tid];
    #pragma unroll 8
    for (int k = 0; k < 384; ++k)
        acc += Wt[(size_t)k * 512 + tid] * qh[k];
    gbuf[tid] = acc;
    __syncthreads();
    if (tid < 128) {
        float iv = sigm(gbuf[tid]);
        float fv = sigm(gbuf[128 + tid]);
        float gv = tanhf(gbuf[256 + tid]);
        float ov = sigm(gbuf[384 + tid]);
        float cn = fv * cl[(size_t)g * 128 + tid] + iv * gv;
        cl[(size_t)g * 128 + tid] = cn;
        hl[(size_t)g * 128 + tid] = ov * tanhf(cn);
    }
}

// attention softmax + weighted sum; out read as bf16 from AB h-half (stride 256)
__global__ __launch_bounds__(256) void k_attnpool(const ushort* __restrict__ AB,
                                                  const float* __restrict__ hl,
                                                  const int* __restrict__ gstart,
                                                  float* __restrict__ qso) {
    int g = blockIdx.x;
    int tid = threadIdx.x, lane = tid & 63, wave = tid >> 6;
    __shared__ float q[DIM];
    __shared__ float wm[4];
    __shared__ float rv[4][DIM];
    __shared__ float sw[4];
    if (tid < DIM) q[tid] = hl[(size_t)g * DIM + tid];
    __syncthreads();
    int s = gstart[g], e = gstart[g + 1];
    float q0 = q[2 * lane], q1 = q[2 * lane + 1];
    float mx = -1e30f;
    for (int node = s + wave; node < e; node += 4) {
        unsigned u = ((const unsigned*)(AB + (size_t)node * 256))[lane];
        float p = b2f(u & 0xffff) * q0 + b2f(u >> 16) * q1;
        #pragma unroll
        for (int off = 1; off < 64; off <<= 1) p += __shfl_xor(p, off);
        mx = fmaxf(mx, p);
    }
    if (lane == 0) wm[wave] = mx;
    __syncthreads();
    mx = fmaxf(fmaxf(wm[0], wm[1]), fmaxf(wm[2], wm[3]));
    float a0 = 0.f, a1 = 0.f, sumw = 0.f;
    for (int node = s + wave; node < e; node += 4) {
        unsigned u = ((const unsigned*)(AB + (size_t)node * 256))[lane];
        float v0 = b2f(u & 0xffff), v1 = b2f(u >> 16);
        float p = v0 * q0 + v1 * q1;
        #pragma unroll
        for (int off = 1; off < 64; off <<= 1) p += __shfl_xor(p, off);
        float wgt = expf(p - mx);
        sumw += wgt;
        a0 += wgt * v0; a1 += wgt * v1;
    }
    rv[wave][2 * lane] = a0;
    rv[wave][2 * lane + 1] = a1;
    if (lane == 0) sw[wave] = sumw;
    __syncthreads();
    if (tid < DIM) {
        float r = rv[0][tid] + rv[1][tid] + rv[2][tid] + rv[3][tid];
        float d = sw[0] + sw[1] + sw[2] + sw[3] + 1e-16f;
        qso[(size_t)g * 2 * DIM + tid] = q[tid];
        qso[(size_t)g * 2 * DIM + DIM + tid] = r / d;
    }
}

// ---------------- launch ----------------
extern "C" void kernel_launch(void* const* d_in, const int* in_sizes, int n_in,
                              void* d_out, int out_size, void* d_ws, size_t ws_size,
                              hipStream_t stream) {
    const float* x        = (const float*)d_in[0];
    const int*   ei       = (const int*)d_in[1];
    const int*   batch    = (const int*)d_in[2];
    const float* lin0_W   = (const float*)d_in[3];
    const float* lin0_b   = (const float*)d_in[4];
    const float* gin_W1   = (const float*)d_in[5];
    const float* gin_b1   = (const float*)d_in[6];
    const float* gin_W2   = (const float*)d_in[7];
    const float* gin_b2   = (const float*)d_in[8];
    const float* gru_Wih  = (const float*)d_in[9];
    const float* gru_Whh  = (const float*)d_in[10];
    const float* gru_bih  = (const float*)d_in[11];
    const float* gru_bhh  = (const float*)d_in[12];
    const float* lstm_Wih = (const float*)d_in[13];
    const float* lstm_Whh = (const float*)d_in[14];
    const float* lstm_bih = (const float*)d_in[15];
    const float* lstm_bhh = (const float*)d_in[16];

    float* qstar_out = (float*)d_out;                         // [NG, 256]
    float* h         = (float*)d_out + (size_t)NG * 2 * DIM;  // [NN, 128] fp32 == `out`

    char* w = (char*)d_ws;
    ushort* AB0   = (ushort*)w; w += (size_t)NN * 256 * 2;   // ping
    ushort* AB1   = (ushort*)w; w += (size_t)NN * 256 * 2;   // pong
    ushort* zt    = (ushort*)w; w += (size_t)NN * 128 * 2;   // aggr out
    ushort* t1    = (ushort*)w; w += (size_t)NN * 128 * 2;   // gin hidden
    ushort* rzb   = (ushort*)w; w += (size_t)NN * 256 * 2;   // [r | z] bf16
    ushort* wlin0 = (ushort*)w; w += 16384 * 2;
    ushort* wg1   = (ushort*)w; w += 16384 * 2;
    ushort* wg2   = (ushort*)w; w += 16384 * 2;
    ushort* wihb  = (ushort*)w; w += 49152 * 2;
    ushort* whhb  = (ushort*)w; w += 49152 * 2;
    ushort* wrz   = (ushort*)w; w += 65536 * 2;
    float* brz    = (float*)w;  w += 256 * 4;
    float* wltr   = (float*)w;  w += (size_t)512 * 384 * 4;  // LSTM W transposed
    float* bl     = (float*)w;  w += 512 * 4;
    float* qstar  = (float*)w;  w += (size_t)NG * 2 * DIM * 4;
    float* hl     = (float*)w;  w += (size_t)NG * DIM * 4;
    float* cl     = (float*)w;  w += (size_t)NG * DIM * 4;
    int* deg      = (int*)w;    w += (size_t)(NN + 1) * 4;
    int* rowptr   = (int*)w;    w += (size_t)(NN + 1) * 4;
    int* cursor   = (int*)w;    w += (size_t)(NN + 1) * 4;
    int* csr_src  = (int*)w;    w += (size_t)NE * 4;
    int* gstart   = (int*)w;    w += (size_t)(NG + 1) * 4;
    int* part     = (int*)w;    w += (size_t)NN * 4;
    int* blksum   = (int*)w;    w += (size_t)(NBLK + 1) * 4;
    int* blkoff   = (int*)w;    w += (size_t)(NBLK + 1) * 4;

    const int* src = ei;
    const int* dst = ei + NE;

    // CSR build + graph ranges (parallel scan)
    k_gstart<<<(NG + 1 + 63) / 64, 64, 0, stream>>>(batch, gstart, NN);
    k_zero_i<<<(NN + 256) / 256, 256, 0, stream>>>(deg, NN + 1);
    k_count<<<(NE + 255) / 256, 256, 0, stream>>>(dst, deg, NE);
    k_scan_blk<<<NBLK, 256, 0, stream>>>(deg, part, blksum);
    k_scan_top<<<1, 256, 0, stream>>>(blksum, blkoff);
    k_scan_add<<<NBLK, 256, 0, stream>>>(part, blkoff, rowptr, cursor);
    k_fill<<<(NE + 255) / 256, 256, 0, stream>>>(src, dst, cursor, csr_src, NE);

    // weights -> bf16 (+ rz pack, LSTM transpose)
    k_f2bv<<<(16384 + 255) / 256, 256, 0, stream>>>(lin0_W, wlin0, 16384);
    k_f2bv<<<(16384 + 255) / 256, 256, 0, stream>>>(gin_W1, wg1, 16384);
    k_f2bv<<<(16384 + 255) / 256, 256, 0, stream>>>(gin_W2, wg2, 16384);
    k_f2bv<<<(49152 + 255) / 256, 256, 0, stream>>>(gru_Wih, wihb, 49152);
    k_f2bv<<<(49152 + 255) / 256, 256, 0, stream>>>(gru_Whh, whhb, 49152);
    k_packrz<<<(65536 + 255) / 256, 256, 0, stream>>>(wihb, whhb, wrz);
    k_biasrz<<<1, 256, 0, stream>>>(gru_bih, gru_bhh, brz);
    k_wtransL<<<(512 * 384 + 255) / 256, 256, 0, stream>>>(lstm_Wih, lstm_Whh, wltr);
    k_biasL<<<2, 256, 0, stream>>>(lstm_bih, lstm_bhh, bl);

    // lin0 -> AB0 h-columns (bf16 only; fp32 h written by last ngate)
    k_lin0<<<782, 256, 0, stream>>>(x, wlin0, lin0_b, AB0, NN);

    // 3 GC layers, ping-pong AB buffers
    for (int t = 0; t < 3; ++t) {
        ushort* ABc = (t & 1) ? AB1 : AB0;
        ushort* ABn = (t & 1) ? AB0 : AB1;
        k_aggr4<<<(NN + 3) / 4, 256, 0, stream>>>(ABc, rowptr, csr_src, zt);
        k_wsgemm<4, 4, 0><<<dim3(782, 1), 256, 0, stream>>>(zt, 128, wg1, gin_b1, t1, 128, 0, NN);
        k_wsgemm<4, 4, 0><<<dim3(782, 1), 256, 0, stream>>>(t1, 128, wg2, gin_b2, ABc, 256, 128, NN);
        k_wsgemm<8, 4, 1><<<dim3(782, 2), 256, 0, stream>>>(ABc, 256, wrz, brz, rzb, 256, 0, NN);
        if (t < 2)
            k_ngate<false><<<1563, 256, 0, stream>>>(ABc, wihb + 256 * 128, whhb + 256 * 128,
                                                     gru_bih + 256, gru_bhh + 256, rzb, h, ABn, NN);
        else
            k_ngate<true><<<1563, 256, 0, stream>>>(ABc, wihb + 256 * 128, whhb + 256 * 128,
                                                    gru_bih + 256, gru_bhh + 256, rzb, h, ABn, NN);
    }
    // final bf16 h lives in AB1 (t=2 wrote ABn=AB1)
    const ushort* ABfin = AB1;

    // Set2Set
    k_zero_f<<<((NG * 2 * DIM + NG * DIM * 2) + 255) / 256, 256, 0, stream>>>(qstar, NG * 2 * DIM + NG * DIM * 2);
    for (int st = 0; st < 3; ++st) {
        k_lstm2<<<NG, 512, 0, stream>>>(qstar, wltr, bl, hl, cl);
        k_attnpool<<<NG, 256, 0, stream>>>(ABfin, hl, gstart, (st == 2) ? qstar_out : qstar);
    }
}

// Round 9
// 504.754 us; speedup vs baseline: 4.9523x; 1.5020x over previous
//
#include <hip/hip_runtime.h>
#include <hip/hip_bf16.h>
#include <math.h>

static constexpr int NN  = 50000;   // nodes
static constexpr int NE  = 800000;  // edges
static constexpr int DIM = 128;
static constexpr int NG  = 512;     // graphs
static constexpr int NBLK = (NN + 255) / 256;  // 196 scan blocks

typedef __attribute__((ext_vector_type(8))) short bf16x8;
typedef __attribute__((ext_vector_type(4))) float f32x4;

__device__ __forceinline__ float sigm(float x) { return 1.0f / (1.0f + expf(-x)); }
__device__ __forceinline__ float b2f(ushort u) { return __uint_as_float(((unsigned)u) << 16); }
__device__ __forceinline__ ushort f2b(float f) {
    __hip_bfloat16 h = __float2bfloat16(f);
    return *reinterpret_cast<ushort*>(&h);
}
__device__ __forceinline__ bf16x8 ldb8(const ushort* p) {
    return *reinterpret_cast<const bf16x8*>(p);
}

// ---------------- small utility kernels ----------------
__global__ void k_zero_i(int* __restrict__ p, int n) {
    int i = blockIdx.x * blockDim.x + threadIdx.x;
    if (i < n) p[i] = 0;
}
__global__ void k_zero_f(float* __restrict__ p, int n) {
    int i = blockIdx.x * blockDim.x + threadIdx.x;
    if (i < n) p[i] = 0.0f;
}
__global__ void k_f2bv(const float* __restrict__ s, ushort* __restrict__ d, int n) {
    int i = blockIdx.x * blockDim.x + threadIdx.x;
    if (i < n) d[i] = f2b(s[i]);
}

// Wrz[col][k], col in [0,256): gate g=col>>7 (0=r,1=z), c=col&127.
// AB rows are [h | m]: k<128 multiplies h -> Whh; k>=128 multiplies m -> Wih.
__global__ void k_packrz(const ushort* __restrict__ wih, const ushort* __restrict__ whh,
                         ushort* __restrict__ wrz) {
    int idx = blockIdx.x * blockDim.x + threadIdx.x;
    if (idx >= 256 * 256) return;
    int col = idx >> 8, k = idx & 255;
    int g = col >> 7, c = col & 127;
    int row = g * 128 + c;
    wrz[idx] = (k < 128) ? whh[row * 128 + k] : wih[row * 128 + (k - 128)];
}
__global__ void k_biasrz(const float* __restrict__ bih, const float* __restrict__ bhh,
                         float* __restrict__ brz) {
    int col = blockIdx.x * blockDim.x + threadIdx.x;
    if (col >= 256) return;
    int g = col >> 7, c = col & 127;
    brz[col] = bih[g * 128 + c] + bhh[g * 128 + c];
}

// LSTM weight transpose: Wt[k*512+col] = (k<256) ? Wih[col][k] : Whh[col][k-256]
__global__ void k_wtransL(const float* __restrict__ Wih, const float* __restrict__ Whh,
                          float* __restrict__ Wt) {
    int idx = blockIdx.x * blockDim.x + threadIdx.x;
    if (idx >= 512 * 384) return;
    int k = idx / 512, col = idx % 512;
    Wt[idx] = (k < 256) ? Wih[(size_t)col * 256 + k] : Whh[(size_t)col * 128 + (k - 256)];
}
__global__ void k_biasL(const float* __restrict__ bih, const float* __restrict__ bhh,
                        float* __restrict__ bl) {
    int col = blockIdx.x * blockDim.x + threadIdx.x;
    if (col < 512) bl[col] = bih[col] + bhh[col];
}

// gstart[g] = lower_bound(batch, g)
__global__ void k_gstart(const int* __restrict__ batch, int* __restrict__ gstart, int n) {
    int g = blockIdx.x * blockDim.x + threadIdx.x;
    if (g > NG) return;
    int lo = 0, hi = n;
    while (lo < hi) { int mid = (lo + hi) >> 1; if (batch[mid] < g) lo = mid + 1; else hi = mid; }
    gstart[g] = lo;
}

__global__ void k_count(const int* __restrict__ dst, int* __restrict__ deg, int e) {
    int i = blockIdx.x * blockDim.x + threadIdx.x;
    if (i < e) atomicAdd(&deg[dst[i]], 1);
}

// ---------------- parallel 3-phase exclusive scan of deg -> rowptr/cursor ----------------
__global__ __launch_bounds__(256) void k_scan_blk(const int* __restrict__ deg,
                                                  int* __restrict__ part,
                                                  int* __restrict__ blksum) {
    __shared__ int s[256];
    int b = blockIdx.x, t = threadIdx.x;
    int i = b * 256 + t;
    int v = (i < NN) ? deg[i] : 0;
    s[t] = v;
    __syncthreads();
    #pragma unroll
    for (int off = 1; off < 256; off <<= 1) {
        int x = (t >= off) ? s[t - off] : 0;
        __syncthreads();
        s[t] += x;
        __syncthreads();
    }
    if (i < NN) part[i] = s[t] - v;
    if (t == 255) blksum[b] = s[255];
}
__global__ __launch_bounds__(256) void k_scan_top(const int* __restrict__ blksum,
                                                  int* __restrict__ blkoff) {
    __shared__ int s[256];
    int t = threadIdx.x;
    int v = (t < NBLK) ? blksum[t] : 0;
    s[t] = v;
    __syncthreads();
    #pragma unroll
    for (int off = 1; off < 256; off <<= 1) {
        int x = (t >= off) ? s[t - off] : 0;
        __syncthreads();
        s[t] += x;
        __syncthreads();
    }
    if (t < NBLK) blkoff[t] = s[t] - v;
    if (t == NBLK - 1) blkoff[NBLK] = s[t];
}
__global__ __launch_bounds__(256) void k_scan_add(const int* __restrict__ part,
                                                  const int* __restrict__ blkoff,
                                                  int* __restrict__ rowptr,
                                                  int* __restrict__ cursor) {
    int b = blockIdx.x, t = threadIdx.x;
    int i = b * 256 + t;
    if (i < NN) {
        int r = part[i] + blkoff[b];
        rowptr[i] = r;
        cursor[i] = r;
    }
    if (b == 0 && t == 0) rowptr[NN] = blkoff[NBLK];
}

__global__ void k_fill(const int* __restrict__ src, const int* __restrict__ dst,
                       int* __restrict__ cursor, int* __restrict__ csr_src, int e) {
    int i = blockIdx.x * blockDim.x + threadIdx.x;
    if (i < e) {
        int d = dst[i];
        int pos = atomicAdd(&cursor[d], 1);
        csr_src[pos] = src[i];
    }
}

// z[i] = h[i] + sum h[nbr]; unroll-by-8 gather, independent acc chains (8x MLP)
__global__ __launch_bounds__(256) void k_aggr8(const ushort* __restrict__ AB,
                                               const int* __restrict__ rowptr,
                                               const int* __restrict__ csr,
                                               ushort* __restrict__ Z) {
    int node = blockIdx.x * 4 + (threadIdx.x >> 6);
    if (node >= NN) return;
    int lane = threadIdx.x & 63;
    const unsigned* base = (const unsigned*)AB;
    unsigned u = base[(size_t)node * 128 + lane];
    float s0a = b2f(u & 0xffff), s0b = b2f(u >> 16);
    float s1a = 0.f, s1b = 0.f, s2a = 0.f, s2b = 0.f, s3a = 0.f, s3b = 0.f;
    float s4a = 0.f, s4b = 0.f, s5a = 0.f, s5b = 0.f, s6a = 0.f, s6b = 0.f, s7a = 0.f, s7b = 0.f;
    int p = rowptr[node], p1 = rowptr[node + 1];
    for (; p + 8 <= p1; p += 8) {
        unsigned v0 = base[(size_t)csr[p + 0] * 128 + lane];
        unsigned v1 = base[(size_t)csr[p + 1] * 128 + lane];
        unsigned v2 = base[(size_t)csr[p + 2] * 128 + lane];
        unsigned v3 = base[(size_t)csr[p + 3] * 128 + lane];
        unsigned v4 = base[(size_t)csr[p + 4] * 128 + lane];
        unsigned v5 = base[(size_t)csr[p + 5] * 128 + lane];
        unsigned v6 = base[(size_t)csr[p + 6] * 128 + lane];
        unsigned v7 = base[(size_t)csr[p + 7] * 128 + lane];
        s0a += b2f(v0 & 0xffff); s0b += b2f(v0 >> 16);
        s1a += b2f(v1 & 0xffff); s1b += b2f(v1 >> 16);
        s2a += b2f(v2 & 0xffff); s2b += b2f(v2 >> 16);
        s3a += b2f(v3 & 0xffff); s3b += b2f(v3 >> 16);
        s4a += b2f(v4 & 0xffff); s4b += b2f(v4 >> 16);
        s5a += b2f(v5 & 0xffff); s5b += b2f(v5 >> 16);
        s6a += b2f(v6 & 0xffff); s6b += b2f(v6 >> 16);
        s7a += b2f(v7 & 0xffff); s7b += b2f(v7 >> 16);
    }
    for (; p < p1; ++p) {
        unsigned v = base[(size_t)csr[p] * 128 + lane];
        s0a += b2f(v & 0xffff); s0b += b2f(v >> 16);
    }
    s0a += (s1a + s2a) + (s3a + s4a) + (s5a + s6a) + s7a;
    s0b += (s1b + s2b) + (s3b + s4b) + (s5b + s6b) + s7b;
    unsigned o = ((unsigned)f2b(s0b) << 16) | (unsigned)f2b(s0a);
    ((unsigned*)(Z + (size_t)node * 128))[lane] = o;
}

// lin0: h = relu(x @ W^T + b), fp32 A; writes AB[:,0:128] bf16
__global__ __launch_bounds__(256) void k_lin0(const float* __restrict__ X,
                                              const ushort* __restrict__ W,
                                              const float* __restrict__ bias,
                                              ushort* __restrict__ AB, int n) {
    int lane = threadIdx.x & 63, wave = threadIdx.x >> 6;
    int c0 = lane & 15, kg = (lane >> 4) * 8;
    int tb0 = wave * 32;
    bf16x8 B[2][4];
    #pragma unroll
    for (int t = 0; t < 2; ++t)
        #pragma unroll
        for (int kk = 0; kk < 4; ++kk)
            B[t][kk] = ldb8(W + (size_t)(tb0 + t * 16 + c0) * 128 + kk * 32 + kg);

    for (int m0 = blockIdx.x * 64; m0 < n; m0 += gridDim.x * 64) {
        f32x4 acc[4][2];
        #pragma unroll
        for (int m = 0; m < 4; ++m) { acc[m][0] = {0,0,0,0}; acc[m][1] = {0,0,0,0}; }
        #pragma unroll
        for (int kk = 0; kk < 4; ++kk) {
            #pragma unroll
            for (int m = 0; m < 4; ++m) {
                int ar = min(m0 + m * 16 + c0, n - 1);
                const float* a = X + (size_t)ar * 128 + kk * 32 + kg;
                float4 x0 = *reinterpret_cast<const float4*>(a);
                float4 x1 = *reinterpret_cast<const float4*>(a + 4);
                bf16x8 af;
                af[0] = (short)f2b(x0.x); af[1] = (short)f2b(x0.y);
                af[2] = (short)f2b(x0.z); af[3] = (short)f2b(x0.w);
                af[4] = (short)f2b(x1.x); af[5] = (short)f2b(x1.y);
                af[6] = (short)f2b(x1.z); af[7] = (short)f2b(x1.w);
                acc[m][0] = __builtin_amdgcn_mfma_f32_16x16x32_bf16(af, B[0][kk], acc[m][0], 0, 0, 0);
                acc[m][1] = __builtin_amdgcn_mfma_f32_16x16x32_bf16(af, B[1][kk], acc[m][1], 0, 0, 0);
            }
        }
        #pragma unroll
        for (int m = 0; m < 4; ++m) {
            int rbase = m0 + m * 16 + ((lane >> 4) << 2);
            #pragma unroll
            for (int t = 0; t < 2; ++t) {
                int col = tb0 + t * 16 + c0;
                float bv = bias[col];
                #pragma unroll
                for (int j = 0; j < 4; ++j) {
                    int row = rbase + j;
                    if (row < n) {
                        float v = fmaxf(acc[m][t][j] + bv, 0.f);
                        AB[(size_t)row * 256 + col] = f2b(v);
                    }
                }
            }
        }
    }
}

// ---------------- fused GIN MLP: m = relu(relu(z@W1^T+b1)@W2^T+b2) -> AB m-half ----------------
// 512 thr / 8 waves; 32-row tiles; z staged + m1 handed off in LDS (stride 136).
__global__ __launch_bounds__(512) void k_ginmlp(const ushort* __restrict__ Zt,
                                                const ushort* __restrict__ W1,
                                                const float* __restrict__ b1,
                                                const ushort* __restrict__ W2,
                                                const float* __restrict__ b2,
                                                ushort* __restrict__ AB, int n) {
    __shared__ ushort Z_lds[32 * 136];
    __shared__ ushort M_lds[32 * 136];
    int tid = threadIdx.x;
    int lane = tid & 63, wave = tid >> 6;
    int c0 = lane & 15, kg = (lane >> 4) * 8;
    int colw = wave * 16 + c0;

    bf16x8 B1[4], B2[4];
    #pragma unroll
    for (int kk = 0; kk < 4; ++kk) {
        B1[kk] = ldb8(W1 + (size_t)colw * 128 + kk * 32 + kg);
        B2[kk] = ldb8(W2 + (size_t)colw * 128 + kk * 32 + kg);
    }
    float bv1 = b1[colw], bv2 = b2[colw];

    for (int m0 = blockIdx.x * 32; m0 < n; m0 += gridDim.x * 32) {
        {   // stage z
            int idx = tid * 8;
            int row = idx >> 7, col = idx & 127;
            int gr = min(m0 + row, n - 1);
            *reinterpret_cast<bf16x8*>(&Z_lds[row * 136 + col]) = ldb8(Zt + (size_t)gr * 128 + col);
        }
        __syncthreads();
        // phase 1: m1 = relu(z @ W1^T + b1) -> M_lds
        f32x4 a1[2] = {{0,0,0,0},{0,0,0,0}};
        #pragma unroll
        for (int kk = 0; kk < 4; ++kk) {
            bf16x8 f0 = *reinterpret_cast<const bf16x8*>(&Z_lds[(c0) * 136 + kk * 32 + kg]);
            bf16x8 f1 = *reinterpret_cast<const bf16x8*>(&Z_lds[(16 + c0) * 136 + kk * 32 + kg]);
            a1[0] = __builtin_amdgcn_mfma_f32_16x16x32_bf16(f0, B1[kk], a1[0], 0, 0, 0);
            a1[1] = __builtin_amdgcn_mfma_f32_16x16x32_bf16(f1, B1[kk], a1[1], 0, 0, 0);
        }
        #pragma unroll
        for (int m = 0; m < 2; ++m)
            #pragma unroll
            for (int j = 0; j < 4; ++j) {
                int row = m * 16 + ((lane >> 4) << 2) + j;
                M_lds[row * 136 + colw] = f2b(fmaxf(a1[m][j] + bv1, 0.f));
            }
        __syncthreads();
        // phase 2: m = relu(m1 @ W2^T + b2) -> AB[:,128:256]
        f32x4 a2[2] = {{0,0,0,0},{0,0,0,0}};
        #pragma unroll
        for (int kk = 0; kk < 4; ++kk) {
            bf16x8 f0 = *reinterpret_cast<const bf16x8*>(&M_lds[(c0) * 136 + kk * 32 + kg]);
            bf16x8 f1 = *reinterpret_cast<const bf16x8*>(&M_lds[(16 + c0) * 136 + kk * 32 + kg]);
            a2[0] = __builtin_amdgcn_mfma_f32_16x16x32_bf16(f0, B2[kk], a2[0], 0, 0, 0);
            a2[1] = __builtin_amdgcn_mfma_f32_16x16x32_bf16(f1, B2[kk], a2[1], 0, 0, 0);
        }
        #pragma unroll
        for (int m = 0; m < 2; ++m)
            #pragma unroll
            for (int j = 0; j < 4; ++j) {
                int row = m * 16 + ((lane >> 4) << 2) + j;
                int grow = m0 + row;
                if (grow < n)
                    AB[(size_t)grow * 256 + 128 + colw] = f2b(fmaxf(a2[m][j] + bv2, 0.f));
            }
        __syncthreads();
    }
}

// ---------------- fused GRU: rz (K=256) + n-gate + combine, LDS handoff ----------------
// 512 thr / 8 waves; 32-row tiles; A=[h|m] staged in LDS (stride 264), rz in LDS.
template<bool WRITEH>
__global__ __launch_bounds__(512) void k_gru3(const ushort* __restrict__ ABin,
                                              const ushort* __restrict__ wrz,
                                              const float* __restrict__ brz,
                                              const ushort* __restrict__ Wn,
                                              const ushort* __restrict__ Un,
                                              const float* __restrict__ bin,
                                              const float* __restrict__ bhn,
                                              float* __restrict__ Hf,
                                              ushort* __restrict__ ABout, int n) {
    __shared__ ushort A_lds[32 * 264];
    __shared__ ushort rz_lds[32 * 264];
    int tid = threadIdx.x;
    int lane = tid & 63, wave = tid >> 6;
    int c0 = lane & 15, kg = (lane >> 4) * 8;

    // persistent B-fragments
    bf16x8 Brz[2][8];
    #pragma unroll
    for (int tt = 0; tt < 2; ++tt)
        #pragma unroll
        for (int kk = 0; kk < 8; ++kk)
            Brz[tt][kk] = ldb8(wrz + (size_t)(wave * 32 + tt * 16 + c0) * 256 + kk * 32 + kg);
    int colN = wave * 16 + c0;
    bf16x8 Bn[4], Bu[4];
    #pragma unroll
    for (int kk = 0; kk < 4; ++kk) {
        Bn[kk] = ldb8(Wn + (size_t)colN * 128 + kk * 32 + kg);
        Bu[kk] = ldb8(Un + (size_t)colN * 128 + kk * 32 + kg);
    }
    float biN = bin[colN], bhN = bhn[colN];
    float bvrz0 = brz[wave * 32 + c0], bvrz1 = brz[wave * 32 + 16 + c0];

    for (int m0 = blockIdx.x * 32; m0 < n; m0 += gridDim.x * 32) {
        // stage A = ABin rows [m0, m0+32) x 256 cols
        #pragma unroll
        for (int pass = 0; pass < 2; ++pass) {
            int idx = pass * 4096 + tid * 8;
            int row = idx >> 8, col = idx & 255;
            int gr = min(m0 + row, n - 1);
            *reinterpret_cast<bf16x8*>(&A_lds[row * 264 + col]) = ldb8(ABin + (size_t)gr * 256 + col);
        }
        __syncthreads();
        // phase 1: rz = sigm([h|m] @ Wrz^T + brz), cols [32w, 32w+32)
        f32x4 acc[2][2];
        acc[0][0] = {0,0,0,0}; acc[0][1] = {0,0,0,0};
        acc[1][0] = {0,0,0,0}; acc[1][1] = {0,0,0,0};
        #pragma unroll
        for (int kk = 0; kk < 8; ++kk) {
            bf16x8 f0 = *reinterpret_cast<const bf16x8*>(&A_lds[(c0) * 264 + kk * 32 + kg]);
            bf16x8 f1 = *reinterpret_cast<const bf16x8*>(&A_lds[(16 + c0) * 264 + kk * 32 + kg]);
            acc[0][0] = __builtin_amdgcn_mfma_f32_16x16x32_bf16(f0, Brz[0][kk], acc[0][0], 0, 0, 0);
            acc[0][1] = __builtin_amdgcn_mfma_f32_16x16x32_bf16(f0, Brz[1][kk], acc[0][1], 0, 0, 0);
            acc[1][0] = __builtin_amdgcn_mfma_f32_16x16x32_bf16(f1, Brz[0][kk], acc[1][0], 0, 0, 0);
            acc[1][1] = __builtin_amdgcn_mfma_f32_16x16x32_bf16(f1, Brz[1][kk], acc[1][1], 0, 0, 0);
        }
        #pragma unroll
        for (int m = 0; m < 2; ++m)
            #pragma unroll
            for (int j = 0; j < 4; ++j) {
                int row = m * 16 + ((lane >> 4) << 2) + j;
                rz_lds[row * 264 + wave * 32 + c0]      = f2b(sigm(acc[m][0][j] + bvrz0));
                rz_lds[row * 264 + wave * 32 + 16 + c0] = f2b(sigm(acc[m][1][j] + bvrz1));
            }
        __syncthreads();
        // phase 2: n-gate (K=128 x2) + combine, cols [16w, 16w+16)
        f32x4 an[2] = {{0,0,0,0},{0,0,0,0}};
        f32x4 au[2] = {{0,0,0,0},{0,0,0,0}};
        #pragma unroll
        for (int kk = 0; kk < 4; ++kk) {
            bf16x8 am0 = *reinterpret_cast<const bf16x8*>(&A_lds[(c0) * 264 + 128 + kk * 32 + kg]);
            bf16x8 ah0 = *reinterpret_cast<const bf16x8*>(&A_lds[(c0) * 264 + kk * 32 + kg]);
            bf16x8 am1 = *reinterpret_cast<const bf16x8*>(&A_lds[(16 + c0) * 264 + 128 + kk * 32 + kg]);
            bf16x8 ah1 = *reinterpret_cast<const bf16x8*>(&A_lds[(16 + c0) * 264 + kk * 32 + kg]);
            an[0] = __builtin_amdgcn_mfma_f32_16x16x32_bf16(am0, Bn[kk], an[0], 0, 0, 0);
            au[0] = __builtin_amdgcn_mfma_f32_16x16x32_bf16(ah0, Bu[kk], au[0], 0, 0, 0);
            an[1] = __builtin_amdgcn_mfma_f32_16x16x32_bf16(am1, Bn[kk], an[1], 0, 0, 0);
            au[1] = __builtin_amdgcn_mfma_f32_16x16x32_bf16(ah1, Bu[kk], au[1], 0, 0, 0);
        }
        #pragma unroll
        for (int m = 0; m < 2; ++m)
            #pragma unroll
            for (int j = 0; j < 4; ++j) {
                int row = m * 16 + ((lane >> 4) << 2) + j;
                int grow = m0 + row;
                if (grow < n) {
                    float r  = b2f(rz_lds[row * 264 + colN]);
                    float zt = b2f(rz_lds[row * 264 + 128 + colN]);
                    float hold = b2f(A_lds[row * 264 + colN]);
                    float nn = tanhf(an[m][j] + biN + r * (au[m][j] + bhN));
                    float hn = (1.f - zt) * nn + zt * hold;
                    ABout[(size_t)grow * 256 + colN] = f2b(hn);
                    if (WRITEH) Hf[(size_t)grow * 128 + colN] = hn;
                }
            }
        __syncthreads();
    }
}

// ---------------- Set2Set ----------------
__global__ __launch_bounds__(512) void k_lstm2(const float* __restrict__ qstar,
                                               const float* __restrict__ Wt,
                                               const float* __restrict__ bl,
                                               float* __restrict__ hl,
                                               float* __restrict__ cl) {
    int g = blockIdx.x, tid = threadIdx.x;
    __shared__ float qh[384];
    __shared__ float gbuf[512];
    if (tid < 256) qh[tid] = qstar[(size_t)g * 256 + tid];
    else if (tid < 384) qh[tid] = hl[(size_t)g * 128 + (tid - 256)];
    __syncthreads();
    float acc = bl[tid];
    #pragma unroll 8
    for (int k = 0; k < 384; ++k)
        acc += Wt[(size_t)k * 512 + tid] * qh[k];
    gbuf[tid] = acc;
    __syncthreads();
    if (tid < 128) {
        float iv = sigm(gbuf[tid]);
        float fv = sigm(gbuf[128 + tid]);
        float gv = tanhf(gbuf[256 + tid]);
        float ov = sigm(gbuf[384 + tid]);
        float cn = fv * cl[(size_t)g * 128 + tid] + iv * gv;
        cl[(size_t)g * 128 + tid] = cn;
        hl[(size_t)g * 128 + tid] = ov * tanhf(cn);
    }
}

// one-pass online-softmax attention pool; out read as bf16 from AB h-half (stride 256)
__global__ __launch_bounds__(256) void k_attnpool(const ushort* __restrict__ AB,
                                                  const float* __restrict__ hl,
                                                  const int* __restrict__ gstart,
                                                  float* __restrict__ qso) {
    int g = blockIdx.x;
    int tid = threadIdx.x, lane = tid & 63, wave = tid >> 6;
    __shared__ float q[DIM];
    __shared__ float wm[4];
    __shared__ float rv[4][DIM];
    __shared__ float sw[4];
    if (tid < DIM) q[tid] = hl[(size_t)g * DIM + tid];
    __syncthreads();
    int s = gstart[g], e = gstart[g + 1];
    float q0 = q[2 * lane], q1 = q[2 * lane + 1];
    float mx = -1e30f, sumw = 0.f, a0 = 0.f, a1 = 0.f;
    for (int node = s + wave; node < e; node += 4) {
        unsigned u = ((const unsigned*)(AB + (size_t)node * 256))[lane];
        float v0 = b2f(u & 0xffff), v1 = b2f(u >> 16);
        float p = v0 * q0 + v1 * q1;
        #pragma unroll
        for (int off = 1; off < 64; off <<= 1) p += __shfl_xor(p, off);
        float nm = fmaxf(mx, p);
        float corr = expf(mx - nm);
        float wgt = expf(p - nm);
        sumw = sumw * corr + wgt;
        a0 = a0 * corr + wgt * v0;
        a1 = a1 * corr + wgt * v1;
        mx = nm;
    }
    if (lane == 0) wm[wave] = mx;
    __syncthreads();
    float gm = fmaxf(fmaxf(wm[0], wm[1]), fmaxf(wm[2], wm[3]));
    float cw = expf(mx - gm);
    rv[wave][2 * lane] = a0 * cw;
    rv[wave][2 * lane + 1] = a1 * cw;
    if (lane == 0) sw[wave] = sumw * cw;
    __syncthreads();
    if (tid < DIM) {
        float r = rv[0][tid] + rv[1][tid] + rv[2][tid] + rv[3][tid];
        float d = sw[0] + sw[1] + sw[2] + sw[3] + 1e-16f;
        qso[(size_t)g * 2 * DIM + tid] = q[tid];
        qso[(size_t)g * 2 * DIM + DIM + tid] = r / d;
    }
}

// ---------------- launch ----------------
extern "C" void kernel_launch(void* const* d_in, const int* in_sizes, int n_in,
                              void* d_out, int out_size, void* d_ws, size_t ws_size,
                              hipStream_t stream) {
    const float* x        = (const float*)d_in[0];
    const int*   ei       = (const int*)d_in[1];
    const int*   batch    = (const int*)d_in[2];
    const float* lin0_W   = (const float*)d_in[3];
    const float* lin0_b   = (const float*)d_in[4];
    const float* gin_W1   = (const float*)d_in[5];
    const float* gin_b1   = (const float*)d_in[6];
    const float* gin_W2   = (const float*)d_in[7];
    const float* gin_b2   = (const float*)d_in[8];
    const float* gru_Wih  = (const float*)d_in[9];
    const float* gru_Whh  = (const float*)d_in[10];
    const float* gru_bih  = (const float*)d_in[11];
    const float* gru_bhh  = (const float*)d_in[12];
    const float* lstm_Wih = (const float*)d_in[13];
    const float* lstm_Whh = (const float*)d_in[14];
    const float* lstm_bih = (const float*)d_in[15];
    const float* lstm_bhh = (const float*)d_in[16];

    float* qstar_out = (float*)d_out;                         // [NG, 256]
    float* h         = (float*)d_out + (size_t)NG * 2 * DIM;  // [NN, 128] fp32 == `out`

    char* w = (char*)d_ws;
    ushort* AB0   = (ushort*)w; w += (size_t)NN * 256 * 2;   // ping
    ushort* AB1   = (ushort*)w; w += (size_t)NN * 256 * 2;   // pong
    ushort* zt    = (ushort*)w; w += (size_t)NN * 128 * 2;   // aggr out
    ushort* wlin0 = (ushort*)w; w += 16384 * 2;
    ushort* wg1   = (ushort*)w; w += 16384 * 2;
    ushort* wg2   = (ushort*)w; w += 16384 * 2;
    ushort* wihb  = (ushort*)w; w += 49152 * 2;
    ushort* whhb  = (ushort*)w; w += 49152 * 2;
    ushort* wrz   = (ushort*)w; w += 65536 * 2;
    float* brz    = (float*)w;  w += 256 * 4;
    float* wltr   = (float*)w;  w += (size_t)512 * 384 * 4;  // LSTM W transposed
    float* bl     = (float*)w;  w += 512 * 4;
    float* qstar  = (float*)w;  w += (size_t)NG * 2 * DIM * 4;
    float* hl     = (float*)w;  w += (size_t)NG * DIM * 4;
    float* cl     = (float*)w;  w += (size_t)NG * DIM * 4;
    int* deg      = (int*)w;    w += (size_t)(NN + 1) * 4;
    int* rowptr   = (int*)w;    w += (size_t)(NN + 1) * 4;
    int* cursor   = (int*)w;    w += (size_t)(NN + 1) * 4;
    int* csr_src  = (int*)w;    w += (size_t)NE * 4;
    int* gstart   = (int*)w;    w += (size_t)(NG + 1) * 4;
    int* part     = (int*)w;    w += (size_t)NN * 4;
    int* blksum   = (int*)w;    w += (size_t)(NBLK + 1) * 4;
    int* blkoff   = (int*)w;    w += (size_t)(NBLK + 1) * 4;

    const int* src = ei;
    const int* dst = ei + NE;

    // CSR build + graph ranges (parallel scan)
    k_gstart<<<(NG + 1 + 63) / 64, 64, 0, stream>>>(batch, gstart, NN);
    k_zero_i<<<(NN + 256) / 256, 256, 0, stream>>>(deg, NN + 1);
    k_count<<<(NE + 255) / 256, 256, 0, stream>>>(dst, deg, NE);
    k_scan_blk<<<NBLK, 256, 0, stream>>>(deg, part, blksum);
    k_scan_top<<<1, 256, 0, stream>>>(blksum, blkoff);
    k_scan_add<<<NBLK, 256, 0, stream>>>(part, blkoff, rowptr, cursor);
    k_fill<<<(NE + 255) / 256, 256, 0, stream>>>(src, dst, cursor, csr_src, NE);

    // weights -> bf16 (+ rz pack, LSTM transpose)
    k_f2bv<<<(16384 + 255) / 256, 256, 0, stream>>>(lin0_W, wlin0, 16384);
    k_f2bv<<<(16384 + 255) / 256, 256, 0, stream>>>(gin_W1, wg1, 16384);
    k_f2bv<<<(16384 + 255) / 256, 256, 0, stream>>>(gin_W2, wg2, 16384);
    k_f2bv<<<(49152 + 255) / 256, 256, 0, stream>>>(gru_Wih, wihb, 49152);
    k_f2bv<<<(49152 + 255) / 256, 256, 0, stream>>>(gru_Whh, whhb, 49152);
    k_packrz<<<(65536 + 255) / 256, 256, 0, stream>>>(wihb, whhb, wrz);
    k_biasrz<<<1, 256, 0, stream>>>(gru_bih, gru_bhh, brz);
    k_wtransL<<<(512 * 384 + 255) / 256, 256, 0, stream>>>(lstm_Wih, lstm_Whh, wltr);
    k_biasL<<<2, 256, 0, stream>>>(lstm_bih, lstm_bhh, bl);

    // lin0 -> AB0 h-columns
    k_lin0<<<782, 256, 0, stream>>>(x, wlin0, lin0_b, AB0, NN);

    // 3 GC layers, ping-pong AB buffers
    for (int t = 0; t < 3; ++t) {
        ushort* ABc = (t & 1) ? AB1 : AB0;
        ushort* ABn = (t & 1) ? AB0 : AB1;
        k_aggr8<<<(NN + 3) / 4, 256, 0, stream>>>(ABc, rowptr, csr_src, zt);
        k_ginmlp<<<512, 512, 0, stream>>>(zt, wg1, gin_b1, wg2, gin_b2, ABc, NN);
        if (t < 2)
            k_gru3<false><<<256, 512, 0, stream>>>(ABc, wrz, brz, wihb + 256 * 128, whhb + 256 * 128,
                                                   gru_bih + 256, gru_bhh + 256, h, ABn, NN);
        else
            k_gru3<true><<<256, 512, 0, stream>>>(ABc, wrz, brz, wihb + 256 * 128, whhb + 256 * 128,
                                                  gru_bih + 256, gru_bhh + 256, h, ABn, NN);
    }
    // final bf16 h lives in AB1 (t=2 wrote ABn=AB1)
    const ushort* ABfin = AB1;

    // Set2Set
    k_zero_f<<<((NG * 2 * DIM + NG * DIM * 2) + 255) / 256, 256, 0, stream>>>(qstar, NG * 2 * DIM + NG * DIM * 2);
    for (int st = 0; st < 3; ++st) {
        k_lstm2<<<NG, 512, 0, stream>>>(qstar, wltr, bl, hl, cl);
        k_attnpool<<<NG, 256, 0, stream>>>(ABfin, hl, gstart, (st == 2) ? qstar_out : qstar);
    }
}